// Round 1
// baseline (5104.271 us; speedup 1.0000x reference)
//
#include <hip/hip_runtime.h>

// -------------------- kernels --------------------

__global__ __launch_bounds__(256) void k_deg(const int* __restrict__ dst,
                                             float* __restrict__ deg, int E) {
    int e = blockIdx.x * 256 + threadIdx.x;
    if (e < E) atomicAdd(&deg[dst[e]], 1.0f);
}

__global__ __launch_bounds__(256) void k_dinv(float* deg, int n) {
    int i = blockIdx.x * 256 + threadIdx.x;
    if (i < n) deg[i] = rsqrtf(deg[i] + 1.0f);  // +1 self-loop; deg>=1 so no zero case
}

// G[i][c] = dinv[i] * sum_k X[i][k] * W[k][c]
template <int D_OUT>
__global__ __launch_bounds__(256) void k_gemm_scaled(const float* __restrict__ X,
                                                     const float* __restrict__ W,
                                                     const float* __restrict__ dinv,
                                                     float* __restrict__ G, int n) {
    constexpr int D_IN = 128;
    constexpr int ROWS = 16;
    __shared__ float Ws[D_IN * D_OUT];
    __shared__ float Xs[ROWS][D_IN];

    const int tid = threadIdx.x;
    const int row0 = blockIdx.x * ROWS;

    // stage W (full) into LDS, float4
    for (int idx = tid * 4; idx < D_IN * D_OUT; idx += 256 * 4) {
        *(float4*)&Ws[idx] = *(const float4*)&W[idx];
    }
    // stage X tile
    for (int idx = tid * 4; idx < ROWS * D_IN; idx += 256 * 4) {
        int r = idx / D_IN, k = idx % D_IN;
        int gr = row0 + r;
        float4 v = make_float4(0.f, 0.f, 0.f, 0.f);
        if (gr < n) v = *(const float4*)&X[(size_t)gr * D_IN + k];
        *(float4*)&Xs[r][k] = v;
    }
    __syncthreads();

    constexpr int GROUPS = 256 / D_OUT;   // 2 (D=128) or 4 (D=64)
    constexpr int RPT = ROWS / GROUPS;    // 8 or 4
    const int c = tid % D_OUT;
    const int rg = tid / D_OUT;

    float acc[RPT];
#pragma unroll
    for (int r = 0; r < RPT; r++) acc[r] = 0.f;

#pragma unroll 4
    for (int k = 0; k < D_IN; k += 4) {
        float w0 = Ws[(k + 0) * D_OUT + c];
        float w1 = Ws[(k + 1) * D_OUT + c];
        float w2 = Ws[(k + 2) * D_OUT + c];
        float w3 = Ws[(k + 3) * D_OUT + c];
#pragma unroll
        for (int r = 0; r < RPT; r++) {
            float4 xv = *(float4*)&Xs[rg * RPT + r][k];
            acc[r] += xv.x * w0 + xv.y * w1 + xv.z * w2 + xv.w * w3;
        }
    }

#pragma unroll
    for (int r = 0; r < RPT; r++) {
        int gr = row0 + rg * RPT + r;
        if (gr < n) G[(size_t)gr * D_OUT + c] = dinv[gr] * acc[r];
    }
}

// ACC[dst] += G[src]   (vectorized: VEC=D/4 threads per edge, 4 atomics each)
template <int D>
__global__ __launch_bounds__(256) void k_scatter(const int* __restrict__ src,
                                                 const int* __restrict__ dst,
                                                 const float* __restrict__ G,
                                                 float* __restrict__ ACC, int E) {
    constexpr int VEC = D / 4;
    long long tid = (long long)blockIdx.x * 256 + threadIdx.x;
    if (tid >= (long long)E * VEC) return;
    int e = (int)(tid / VEC);
    int j = ((int)(tid & (VEC - 1))) * 4;
    int s = src[e], d = dst[e];
    float4 g = *(const float4*)&G[(size_t)s * D + j];
    float* a = &ACC[(size_t)d * D + j];
    atomicAdd(a + 0, g.x);
    atomicAdd(a + 1, g.y);
    atomicAdd(a + 2, g.z);
    atomicAdd(a + 3, g.w);
}

// H[t] = relu(dinv[i]*(ACC[t]+G[t]) + b[c]); H may alias ACC (elementwise)
template <int D>
__global__ __launch_bounds__(256) void k_finalize(const float* ACC,
                                                  const float* __restrict__ G,
                                                  const float* __restrict__ dinv,
                                                  const float* __restrict__ b,
                                                  float* H, int n) {
    long long t = (long long)blockIdx.x * 256 + threadIdx.x;
    if (t >= (long long)n * D) return;
    int i = (int)(t / D), c = (int)(t % D);
    float v = dinv[i] * (ACC[t] + G[t]) + b[c];
    H[t] = v > 0.f ? v : 0.f;
}

// layer-2 finalize fused with mean-pool accumulation
__global__ __launch_bounds__(256) void k_finalize_pool(const float* __restrict__ ACC,
                                                       const float* __restrict__ G,
                                                       const float* __restrict__ dinv,
                                                       const float* __restrict__ b,
                                                       const int* __restrict__ batch,
                                                       float* __restrict__ pool, int n) {
    long long t = (long long)blockIdx.x * 256 + threadIdx.x;
    if (t >= (long long)n * 64) return;
    int i = (int)(t / 64), c = (int)(t & 63);
    float v = dinv[i] * (ACC[t] + G[t]) + b[c];
    v = v > 0.f ? v : 0.f;
    atomicAdd(&pool[batch[i] * 64 + c], v);
}

__global__ __launch_bounds__(256) void k_count(const int* __restrict__ batch,
                                               float* __restrict__ cnt, int n) {
    int i = blockIdx.x * 256 + threadIdx.x;
    if (i < n) atomicAdd(&cnt[batch[i]], 1.0f);
}

__global__ __launch_bounds__(64) void k_div(const float* __restrict__ pool,
                                            const float* __restrict__ cnt,
                                            float* __restrict__ out) {
    int t = blockIdx.x * 64 + threadIdx.x;  // 64 blocks x 64 threads = 4096
    int g = t >> 6;
    float c = cnt[g];
    c = c > 1.f ? c : 1.f;
    out[t] = pool[t] / c;
}

// -------------------- launch --------------------

extern "C" void kernel_launch(void* const* d_in, const int* in_sizes, int n_in,
                              void* d_out, int out_size, void* d_ws, size_t ws_size,
                              hipStream_t stream) {
    const float* x = (const float*)d_in[0];
    const int* edge = (const int*)d_in[1];
    const int* batch = (const int*)d_in[2];
    const float* W1 = (const float*)d_in[3];
    const float* b1 = (const float*)d_in[4];
    const float* W2 = (const float*)d_in[5];
    const float* b2 = (const float*)d_in[6];

    const int n = in_sizes[0] / 128;
    const int E = in_sizes[1] / 2;
    const int* src = edge;       // edge_index row 0
    const int* dst = edge + E;   // edge_index row 1

    // workspace layout (floats)
    float* ws = (float*)d_ws;
    size_t nAlign = ((size_t)n + 255) & ~(size_t)255;
    float* deg = ws;                              // n (becomes dinv in-place)
    float* bufG = deg + nAlign;                   // n*128
    float* bufA = bufG + (size_t)n * 128;         // n*128
    float* pool = bufA + (size_t)n * 128;         // 64*64
    float* cnt = pool + 64 * 64;                  // 64

    // zero-init (must happen every call; harness does not re-poison)
    hipMemsetAsync(deg, 0, (size_t)n * 4, stream);
    hipMemsetAsync(bufA, 0, (size_t)n * 128 * 4, stream);
    hipMemsetAsync(pool, 0, (64 * 64 + 64) * 4, stream);

    // degree + dinv
    k_deg<<<(E + 255) / 256, 256, 0, stream>>>(dst, deg, E);
    k_dinv<<<(n + 255) / 256, 256, 0, stream>>>(deg, n);

    // ---- layer 1 ----
    k_gemm_scaled<128><<<(n + 15) / 16, 256, 0, stream>>>(x, W1, deg, bufG, n);
    {
        long long tot = (long long)E * 32;
        k_scatter<128><<<(int)((tot + 255) / 256), 256, 0, stream>>>(src, dst, bufG, bufA, E);
    }
    {
        long long tot = (long long)n * 128;
        k_finalize<128><<<(int)((tot + 255) / 256), 256, 0, stream>>>(bufA, bufG, deg, b1,
                                                                      bufA, n);
    }

    // ---- layer 2 ----
    k_gemm_scaled<64><<<(n + 15) / 16, 256, 0, stream>>>(bufA, W2, deg, bufG, n);
    float* acc2 = bufG + (size_t)n * 64;
    hipMemsetAsync(acc2, 0, (size_t)n * 64 * 4, stream);
    {
        long long tot = (long long)E * 16;
        k_scatter<64><<<(int)((tot + 255) / 256), 256, 0, stream>>>(src, dst, bufG, acc2, E);
    }
    k_finalize_pool<<<(int)(((long long)n * 64 + 255) / 256), 256, 0, stream>>>(
        acc2, bufG, deg, b2, batch, pool, n);

    // ---- pooling ----
    k_count<<<(n + 255) / 256, 256, 0, stream>>>(batch, cnt, n);
    k_div<<<64, 64, 0, stream>>>(pool, cnt, (float*)d_out);
}

// Round 2
// 1214.103 us; speedup vs baseline: 4.2041x; 4.2041x over previous
//
#include <hip/hip_runtime.h>

// -------------------- degree / dinv --------------------

__global__ __launch_bounds__(256) void k_hist(const int* __restrict__ dst,
                                              int* __restrict__ cnt, int E) {
    int e = blockIdx.x * 256 + threadIdx.x;
    if (e < E) atomicAdd(&cnt[dst[e]], 1);
}

__global__ __launch_bounds__(256) void k_dinv(const int* __restrict__ cnt,
                                              float* __restrict__ dinv, int n) {
    int i = blockIdx.x * 256 + threadIdx.x;
    if (i < n) dinv[i] = rsqrtf((float)cnt[i] + 1.0f);  // +1 = self-loop
}

// -------------------- prefix scan (3-kernel, 1024 elems/block) --------------------

__global__ __launch_bounds__(256) void k_scan_block(const int* __restrict__ cnt,
                                                    int* __restrict__ excl,
                                                    int* __restrict__ bsum, int n) {
    __shared__ int lds[256];
    const int t = threadIdx.x;
    const int base = blockIdx.x * 1024 + t * 4;
    int v0 = 0, v1 = 0, v2 = 0, v3 = 0;
    if (base + 0 < n) v0 = cnt[base + 0];
    if (base + 1 < n) v1 = cnt[base + 1];
    if (base + 2 < n) v2 = cnt[base + 2];
    if (base + 3 < n) v3 = cnt[base + 3];
    int s = v0 + v1 + v2 + v3;
    lds[t] = s;
    __syncthreads();
    for (int off = 1; off < 256; off <<= 1) {
        int x = (t >= off) ? lds[t - off] : 0;
        __syncthreads();
        lds[t] += x;
        __syncthreads();
    }
    int run = lds[t] - s;  // exclusive prefix of this thread's chunk
    if (t == 255) bsum[blockIdx.x] = lds[255];
    if (base + 0 < n) excl[base + 0] = run; run += v0;
    if (base + 1 < n) excl[base + 1] = run; run += v1;
    if (base + 2 < n) excl[base + 2] = run; run += v2;
    if (base + 3 < n) excl[base + 3] = run;
}

__global__ __launch_bounds__(256) void k_scan_sums(int* __restrict__ bsum, int nb) {
    __shared__ int lds[256];
    const int t = threadIdx.x;
    const int base = t * 4;
    int v0 = 0, v1 = 0, v2 = 0, v3 = 0;
    if (base + 0 < nb) v0 = bsum[base + 0];
    if (base + 1 < nb) v1 = bsum[base + 1];
    if (base + 2 < nb) v2 = bsum[base + 2];
    if (base + 3 < nb) v3 = bsum[base + 3];
    int s = v0 + v1 + v2 + v3;
    lds[t] = s;
    __syncthreads();
    for (int off = 1; off < 256; off <<= 1) {
        int x = (t >= off) ? lds[t - off] : 0;
        __syncthreads();
        lds[t] += x;
        __syncthreads();
    }
    int run = lds[t] - s;
    if (base + 0 < nb) bsum[base + 0] = run; run += v0;
    if (base + 1 < nb) bsum[base + 1] = run; run += v1;
    if (base + 2 < nb) bsum[base + 2] = run; run += v2;
    if (base + 3 < nb) bsum[base + 3] = run;
}

__global__ __launch_bounds__(256) void k_scan_add(int* __restrict__ excl,
                                                  const int* __restrict__ bsum, int n) {
    const int base = blockIdx.x * 1024 + threadIdx.x * 4;
    const int o = bsum[blockIdx.x];
    if (base + 0 < n) excl[base + 0] += o;
    if (base + 1 < n) excl[base + 1] += o;
    if (base + 2 < n) excl[base + 2] += o;
    if (base + 3 < n) excl[base + 3] += o;
}

// csr[cursor[dst]++] = src ; after this kernel cursor[i] == row end
__global__ __launch_bounds__(256) void k_fill(const int* __restrict__ src,
                                              const int* __restrict__ dst,
                                              int* __restrict__ cursor,
                                              int* __restrict__ csr, int E) {
    int e = blockIdx.x * 256 + threadIdx.x;
    if (e < E) {
        int p = atomicAdd(&cursor[dst[e]], 1);
        csr[p] = src[e];
    }
}

// -------------------- GEMM: G[i][c] = dinv[i] * sum_k X[i][k]*W[k][c] --------------------

template <int D_OUT>
__global__ __launch_bounds__(256) void k_gemm_scaled(const float* __restrict__ X,
                                                     const float* __restrict__ W,
                                                     const float* __restrict__ dinv,
                                                     float* __restrict__ G, int n) {
    constexpr int D_IN = 128;
    constexpr int ROWS = 16;
    __shared__ float Ws[D_IN * D_OUT];
    __shared__ float Xs[ROWS][D_IN];

    const int tid = threadIdx.x;
    const int row0 = blockIdx.x * ROWS;

    for (int idx = tid * 4; idx < D_IN * D_OUT; idx += 256 * 4)
        *(float4*)&Ws[idx] = *(const float4*)&W[idx];
    for (int idx = tid * 4; idx < ROWS * D_IN; idx += 256 * 4) {
        int r = idx / D_IN, k = idx % D_IN;
        int gr = row0 + r;
        float4 v = make_float4(0.f, 0.f, 0.f, 0.f);
        if (gr < n) v = *(const float4*)&X[(size_t)gr * D_IN + k];
        *(float4*)&Xs[r][k] = v;
    }
    __syncthreads();

    constexpr int GROUPS = 256 / D_OUT;
    constexpr int RPT = ROWS / GROUPS;
    const int c = tid % D_OUT;
    const int rg = tid / D_OUT;

    float acc[RPT];
#pragma unroll
    for (int r = 0; r < RPT; r++) acc[r] = 0.f;

#pragma unroll 4
    for (int k = 0; k < D_IN; k += 4) {
        float w0 = Ws[(k + 0) * D_OUT + c];
        float w1 = Ws[(k + 1) * D_OUT + c];
        float w2 = Ws[(k + 2) * D_OUT + c];
        float w3 = Ws[(k + 3) * D_OUT + c];
#pragma unroll
        for (int r = 0; r < RPT; r++) {
            float4 xv = *(float4*)&Xs[rg * RPT + r][k];
            acc[r] += xv.x * w0 + xv.y * w1 + xv.z * w2 + xv.w * w3;
        }
    }
#pragma unroll
    for (int r = 0; r < RPT; r++) {
        int gr = row0 + rg * RPT + r;
        if (gr < n) G[(size_t)gr * D_OUT + c] = dinv[gr] * acc[r];
    }
}

// -------------------- layer-1 aggregation: 32 lanes per dst row --------------------

__global__ __launch_bounds__(256) void k_gather128(const int* __restrict__ rowptr,
                                                   const int* __restrict__ rowend,
                                                   const int* __restrict__ csr,
                                                   const float* __restrict__ G,
                                                   const float* __restrict__ dinv,
                                                   const float* __restrict__ b,
                                                   float* __restrict__ H, int n) {
    const int g = blockIdx.x * 8 + threadIdx.x / 32;  // row
    const int lane = threadIdx.x & 31;
    if (g >= n) return;
    const int beg = rowptr[g], end = rowend[g];
    float4 acc = *(const float4*)&G[(size_t)g * 128 + lane * 4];  // self-loop term
    int e = beg;
    for (; e + 1 < end; e += 2) {
        int s0 = csr[e], s1 = csr[e + 1];
        float4 a = *(const float4*)&G[(size_t)s0 * 128 + lane * 4];
        float4 c2 = *(const float4*)&G[(size_t)s1 * 128 + lane * 4];
        acc.x += a.x + c2.x; acc.y += a.y + c2.y;
        acc.z += a.z + c2.z; acc.w += a.w + c2.w;
    }
    if (e < end) {
        int s0 = csr[e];
        float4 a = *(const float4*)&G[(size_t)s0 * 128 + lane * 4];
        acc.x += a.x; acc.y += a.y; acc.z += a.z; acc.w += a.w;
    }
    const float di = dinv[g];
    float4 bb = *(const float4*)&b[lane * 4];
    float4 o;
    o.x = fmaxf(di * acc.x + bb.x, 0.f);
    o.y = fmaxf(di * acc.y + bb.y, 0.f);
    o.z = fmaxf(di * acc.z + bb.z, 0.f);
    o.w = fmaxf(di * acc.w + bb.w, 0.f);
    *(float4*)&H[(size_t)g * 128 + lane * 4] = o;
}

// -------------------- layer-2 aggregation fused with mean-pool accumulate ------------
// 16 lanes per dst row; 16 rows per block; block-level LDS reduction into pool
// (batch is sorted -> a block spans <=2 graphs almost always)

__global__ __launch_bounds__(256) void k_gather64_pool(const int* __restrict__ rowptr,
                                                       const int* __restrict__ rowend,
                                                       const int* __restrict__ csr,
                                                       const float* __restrict__ G,
                                                       const float* __restrict__ dinv,
                                                       const float* __restrict__ b,
                                                       const int* __restrict__ batch,
                                                       float* __restrict__ pool, int n) {
    __shared__ float po[16][68];  // padded: groups land on different banks
    __shared__ int pg[16];
    const int grp = threadIdx.x / 16;
    const int lane = threadIdx.x & 15;
    const int g = blockIdx.x * 16 + grp;

    float4 o = make_float4(0.f, 0.f, 0.f, 0.f);
    if (g < n) {
        const int beg = rowptr[g], end = rowend[g];
        float4 acc = *(const float4*)&G[(size_t)g * 64 + lane * 4];
        int e = beg;
        for (; e + 1 < end; e += 2) {
            int s0 = csr[e], s1 = csr[e + 1];
            float4 a = *(const float4*)&G[(size_t)s0 * 64 + lane * 4];
            float4 c2 = *(const float4*)&G[(size_t)s1 * 64 + lane * 4];
            acc.x += a.x + c2.x; acc.y += a.y + c2.y;
            acc.z += a.z + c2.z; acc.w += a.w + c2.w;
        }
        if (e < end) {
            int s0 = csr[e];
            float4 a = *(const float4*)&G[(size_t)s0 * 64 + lane * 4];
            acc.x += a.x; acc.y += a.y; acc.z += a.z; acc.w += a.w;
        }
        const float di = dinv[g];
        float4 bb = *(const float4*)&b[lane * 4];
        o.x = fmaxf(di * acc.x + bb.x, 0.f);
        o.y = fmaxf(di * acc.y + bb.y, 0.f);
        o.z = fmaxf(di * acc.z + bb.z, 0.f);
        o.w = fmaxf(di * acc.w + bb.w, 0.f);
    }
    if (lane == 0) pg[grp] = (g < n) ? batch[g] : -1;
    *(float4*)&po[grp][lane * 4] = o;
    __syncthreads();

    if (threadIdx.x < 64) {
        const int c = threadIdx.x;
        float run = 0.f;
        int cur = -1;
        for (int r = 0; r < 16; r++) {
            int gr = pg[r];
            if (gr < 0) continue;
            if (gr != cur) {
                if (cur >= 0) atomicAdd(&pool[cur * 64 + c], run);
                cur = gr;
                run = 0.f;
            }
            run += po[r][c];
        }
        if (cur >= 0) atomicAdd(&pool[cur * 64 + c], run);
    }
}

// -------------------- pooling tail --------------------

__global__ __launch_bounds__(256) void k_count(const int* __restrict__ batch,
                                               float* __restrict__ cnt, int n) {
    int i = blockIdx.x * 256 + threadIdx.x;
    if (i < n) atomicAdd(&cnt[batch[i]], 1.0f);
}

__global__ __launch_bounds__(64) void k_div(const float* __restrict__ pool,
                                            const float* __restrict__ cnt,
                                            float* __restrict__ out) {
    int t = blockIdx.x * 64 + threadIdx.x;
    int g = t >> 6;
    float c = cnt[g];
    c = c > 1.f ? c : 1.f;
    out[t] = pool[t] / c;
}

// -------------------- launch --------------------

extern "C" void kernel_launch(void* const* d_in, const int* in_sizes, int n_in,
                              void* d_out, int out_size, void* d_ws, size_t ws_size,
                              hipStream_t stream) {
    const float* x = (const float*)d_in[0];
    const int* edge = (const int*)d_in[1];
    const int* batch = (const int*)d_in[2];
    const float* W1 = (const float*)d_in[3];
    const float* b1 = (const float*)d_in[4];
    const float* W2 = (const float*)d_in[5];
    const float* b2 = (const float*)d_in[6];

    const int n = in_sizes[0] / 128;
    const int E = in_sizes[1] / 2;
    const int* src = edge;
    const int* dst = edge + E;

    // workspace layout
    size_t nA = ((size_t)n + 255) & ~(size_t)255;
    float* dinv = (float*)d_ws;                 // n
    int* cnt = (int*)(dinv + nA);               // n
    int* rowptr = cnt + nA;                     // n
    int* cursor = rowptr + nA;                  // n
    int* bsum = cursor + nA;                    // 1024
    float* pool = (float*)(bsum + 1024);        // 4096
    float* cntG = pool + 4096;                  // 64 (+pad to 256)
    float* bufG = cntG + 256;                   // n*128
    float* bufH = bufG + (size_t)n * 128;       // n*128
    int* csr = (int*)(bufH + (size_t)n * 128);  // E

    hipMemsetAsync(cnt, 0, (size_t)n * 4, stream);
    hipMemsetAsync(pool, 0, (4096 + 64) * 4, stream);

    // CSR build + dinv
    k_hist<<<(E + 255) / 256, 256, 0, stream>>>(dst, cnt, E);
    k_dinv<<<(n + 255) / 256, 256, 0, stream>>>(cnt, dinv, n);
    int nb = (n + 1023) / 1024;
    k_scan_block<<<nb, 256, 0, stream>>>(cnt, rowptr, bsum, n);
    k_scan_sums<<<1, 256, 0, stream>>>(bsum, nb);
    k_scan_add<<<nb, 256, 0, stream>>>(rowptr, bsum, n);
    hipMemcpyAsync(cursor, rowptr, (size_t)n * 4, hipMemcpyDeviceToDevice, stream);
    k_fill<<<(E + 255) / 256, 256, 0, stream>>>(src, dst, cursor, csr, E);

    // layer 1: GEMM (scaled) -> gather-aggregate (+self, relu, bias)
    k_gemm_scaled<128><<<(n + 15) / 16, 256, 0, stream>>>(x, W1, dinv, bufG, n);
    k_gather128<<<(n + 7) / 8, 256, 0, stream>>>(rowptr, cursor, csr, bufG, dinv, b1,
                                                 bufH, n);

    // layer 2: GEMM (scaled) -> gather-aggregate fused with pool
    k_gemm_scaled<64><<<(n + 15) / 16, 256, 0, stream>>>(bufH, W2, dinv, bufG, n);
    k_gather64_pool<<<(n + 15) / 16, 256, 0, stream>>>(rowptr, cursor, csr, bufG, dinv,
                                                       b2, batch, pool, n);

    // mean
    k_count<<<(n + 255) / 256, 256, 0, stream>>>(batch, cntG, n);
    k_div<<<64, 64, 0, stream>>>(pool, cntG, (float*)d_out);
}

// Round 3
// 584.814 us; speedup vs baseline: 8.7280x; 2.0761x over previous
//
#include <hip/hip_runtime.h>

// -------------------- degree / dinv --------------------

__global__ __launch_bounds__(256) void k_hist(const int* __restrict__ dst,
                                              int* __restrict__ cnt, int E) {
    int e = blockIdx.x * 256 + threadIdx.x;
    if (e < E) atomicAdd(&cnt[dst[e]], 1);
}

__global__ __launch_bounds__(256) void k_dinv(const int* __restrict__ cnt,
                                              float* __restrict__ dinv, int n) {
    int i = blockIdx.x * 256 + threadIdx.x;
    if (i < n) dinv[i] = rsqrtf((float)cnt[i] + 1.0f);  // +1 = self-loop
}

// -------------------- prefix scan (3-kernel, 1024 elems/block) --------------------

__global__ __launch_bounds__(256) void k_scan_block(const int* __restrict__ cnt,
                                                    int* __restrict__ excl,
                                                    int* __restrict__ bsum, int n) {
    __shared__ int lds[256];
    const int t = threadIdx.x;
    const int base = blockIdx.x * 1024 + t * 4;
    int v0 = 0, v1 = 0, v2 = 0, v3 = 0;
    if (base + 0 < n) v0 = cnt[base + 0];
    if (base + 1 < n) v1 = cnt[base + 1];
    if (base + 2 < n) v2 = cnt[base + 2];
    if (base + 3 < n) v3 = cnt[base + 3];
    int s = v0 + v1 + v2 + v3;
    lds[t] = s;
    __syncthreads();
    for (int off = 1; off < 256; off <<= 1) {
        int x = (t >= off) ? lds[t - off] : 0;
        __syncthreads();
        lds[t] += x;
        __syncthreads();
    }
    int run = lds[t] - s;  // exclusive prefix of this thread's chunk
    if (t == 255) bsum[blockIdx.x] = lds[255];
    if (base + 0 < n) excl[base + 0] = run; run += v0;
    if (base + 1 < n) excl[base + 1] = run; run += v1;
    if (base + 2 < n) excl[base + 2] = run; run += v2;
    if (base + 3 < n) excl[base + 3] = run;
}

__global__ __launch_bounds__(256) void k_scan_sums(int* __restrict__ bsum, int nb) {
    __shared__ int lds[256];
    const int t = threadIdx.x;
    const int base = t * 4;
    int v0 = 0, v1 = 0, v2 = 0, v3 = 0;
    if (base + 0 < nb) v0 = bsum[base + 0];
    if (base + 1 < nb) v1 = bsum[base + 1];
    if (base + 2 < nb) v2 = bsum[base + 2];
    if (base + 3 < nb) v3 = bsum[base + 3];
    int s = v0 + v1 + v2 + v3;
    lds[t] = s;
    __syncthreads();
    for (int off = 1; off < 256; off <<= 1) {
        int x = (t >= off) ? lds[t - off] : 0;
        __syncthreads();
        lds[t] += x;
        __syncthreads();
    }
    int run = lds[t] - s;
    if (base + 0 < nb) bsum[base + 0] = run; run += v0;
    if (base + 1 < nb) bsum[base + 1] = run; run += v1;
    if (base + 2 < nb) bsum[base + 2] = run; run += v2;
    if (base + 3 < nb) bsum[base + 3] = run;
}

__global__ __launch_bounds__(256) void k_scan_add(int* __restrict__ excl,
                                                  const int* __restrict__ bsum, int n) {
    const int base = blockIdx.x * 1024 + threadIdx.x * 4;
    const int o = bsum[blockIdx.x];
    if (base + 0 < n) excl[base + 0] += o;
    if (base + 1 < n) excl[base + 1] += o;
    if (base + 2 < n) excl[base + 2] += o;
    if (base + 3 < n) excl[base + 3] += o;
}

// csr[cursor[dst]++] = src ; after this kernel cursor[i] == row end
__global__ __launch_bounds__(256) void k_fill(const int* __restrict__ src,
                                              const int* __restrict__ dst,
                                              int* __restrict__ cursor,
                                              int* __restrict__ csr, int E) {
    int e = blockIdx.x * 256 + threadIdx.x;
    if (e < E) {
        int p = atomicAdd(&cursor[dst[e]], 1);
        csr[p] = src[e];
    }
}

// -------------------- GEMM: G[i][c] = dinv[i] * sum_k X[i][k]*W[k][c] --------------------

template <int D_OUT>
__global__ __launch_bounds__(256) void k_gemm_scaled(const float* __restrict__ X,
                                                     const float* __restrict__ W,
                                                     const float* __restrict__ dinv,
                                                     float* __restrict__ G, int n) {
    constexpr int D_IN = 128;
    constexpr int ROWS = 16;
    __shared__ float Ws[D_IN * D_OUT];
    __shared__ float Xs[ROWS][D_IN];

    const int tid = threadIdx.x;
    const int row0 = blockIdx.x * ROWS;

    for (int idx = tid * 4; idx < D_IN * D_OUT; idx += 256 * 4)
        *(float4*)&Ws[idx] = *(const float4*)&W[idx];
    for (int idx = tid * 4; idx < ROWS * D_IN; idx += 256 * 4) {
        int r = idx / D_IN, k = idx % D_IN;
        int gr = row0 + r;
        float4 v = make_float4(0.f, 0.f, 0.f, 0.f);
        if (gr < n) v = *(const float4*)&X[(size_t)gr * D_IN + k];
        *(float4*)&Xs[r][k] = v;
    }
    __syncthreads();

    constexpr int GROUPS = 256 / D_OUT;
    constexpr int RPT = ROWS / GROUPS;
    const int c = tid % D_OUT;
    const int rg = tid / D_OUT;

    float acc[RPT];
#pragma unroll
    for (int r = 0; r < RPT; r++) acc[r] = 0.f;

#pragma unroll 4
    for (int k = 0; k < D_IN; k += 4) {
        float w0 = Ws[(k + 0) * D_OUT + c];
        float w1 = Ws[(k + 1) * D_OUT + c];
        float w2 = Ws[(k + 2) * D_OUT + c];
        float w3 = Ws[(k + 3) * D_OUT + c];
#pragma unroll
        for (int r = 0; r < RPT; r++) {
            float4 xv = *(float4*)&Xs[rg * RPT + r][k];
            acc[r] += xv.x * w0 + xv.y * w1 + xv.z * w2 + xv.w * w3;
        }
    }
#pragma unroll
    for (int r = 0; r < RPT; r++) {
        int gr = row0 + rg * RPT + r;
        if (gr < n) G[(size_t)gr * D_OUT + c] = dinv[gr] * acc[r];
    }
}

// -------------------- layer-1 aggregation: 32 lanes per dst row --------------------

__global__ __launch_bounds__(256) void k_gather128(const int* __restrict__ rowptr,
                                                   const int* __restrict__ rowend,
                                                   const int* __restrict__ csr,
                                                   const float* __restrict__ G,
                                                   const float* __restrict__ dinv,
                                                   const float* __restrict__ b,
                                                   float* __restrict__ H, int n) {
    const int g = blockIdx.x * 8 + threadIdx.x / 32;  // row
    const int lane = threadIdx.x & 31;
    if (g >= n) return;
    const int beg = rowptr[g], end = rowend[g];
    float4 acc = *(const float4*)&G[(size_t)g * 128 + lane * 4];  // self-loop term
    int e = beg;
    for (; e + 1 < end; e += 2) {
        int s0 = csr[e], s1 = csr[e + 1];
        float4 a = *(const float4*)&G[(size_t)s0 * 128 + lane * 4];
        float4 c2 = *(const float4*)&G[(size_t)s1 * 128 + lane * 4];
        acc.x += a.x + c2.x; acc.y += a.y + c2.y;
        acc.z += a.z + c2.z; acc.w += a.w + c2.w;
    }
    if (e < end) {
        int s0 = csr[e];
        float4 a = *(const float4*)&G[(size_t)s0 * 128 + lane * 4];
        acc.x += a.x; acc.y += a.y; acc.z += a.z; acc.w += a.w;
    }
    const float di = dinv[g];
    float4 bb = *(const float4*)&b[lane * 4];
    float4 o;
    o.x = fmaxf(di * acc.x + bb.x, 0.f);
    o.y = fmaxf(di * acc.y + bb.y, 0.f);
    o.z = fmaxf(di * acc.z + bb.z, 0.f);
    o.w = fmaxf(di * acc.w + bb.w, 0.f);
    *(float4*)&H[(size_t)g * 128 + lane * 4] = o;
}

// -------------------- layer-2 aggregation fused with mean-pool accumulate ------------

__global__ __launch_bounds__(256) void k_gather64_pool(const int* __restrict__ rowptr,
                                                       const int* __restrict__ rowend,
                                                       const int* __restrict__ csr,
                                                       const float* __restrict__ G,
                                                       const float* __restrict__ dinv,
                                                       const float* __restrict__ b,
                                                       const int* __restrict__ batch,
                                                       float* __restrict__ pool, int n) {
    __shared__ float po[16][68];
    __shared__ int pg[16];
    const int grp = threadIdx.x / 16;
    const int lane = threadIdx.x & 15;
    const int g = blockIdx.x * 16 + grp;

    float4 o = make_float4(0.f, 0.f, 0.f, 0.f);
    if (g < n) {
        const int beg = rowptr[g], end = rowend[g];
        float4 acc = *(const float4*)&G[(size_t)g * 64 + lane * 4];
        int e = beg;
        for (; e + 1 < end; e += 2) {
            int s0 = csr[e], s1 = csr[e + 1];
            float4 a = *(const float4*)&G[(size_t)s0 * 64 + lane * 4];
            float4 c2 = *(const float4*)&G[(size_t)s1 * 64 + lane * 4];
            acc.x += a.x + c2.x; acc.y += a.y + c2.y;
            acc.z += a.z + c2.z; acc.w += a.w + c2.w;
        }
        if (e < end) {
            int s0 = csr[e];
            float4 a = *(const float4*)&G[(size_t)s0 * 64 + lane * 4];
            acc.x += a.x; acc.y += a.y; acc.z += a.z; acc.w += a.w;
        }
        const float di = dinv[g];
        float4 bb = *(const float4*)&b[lane * 4];
        o.x = fmaxf(di * acc.x + bb.x, 0.f);
        o.y = fmaxf(di * acc.y + bb.y, 0.f);
        o.z = fmaxf(di * acc.z + bb.z, 0.f);
        o.w = fmaxf(di * acc.w + bb.w, 0.f);
    }
    if (lane == 0) pg[grp] = (g < n) ? batch[g] : -1;
    *(float4*)&po[grp][lane * 4] = o;
    __syncthreads();

    if (threadIdx.x < 64) {
        const int c = threadIdx.x;
        float run = 0.f;
        int cur = -1;
        for (int r = 0; r < 16; r++) {
            int gr = pg[r];
            if (gr < 0) continue;
            if (gr != cur) {
                if (cur >= 0) atomicAdd(&pool[cur * 64 + c], run);
                cur = gr;
                run = 0.f;
            }
            run += po[r][c];
        }
        if (cur >= 0) atomicAdd(&pool[cur * 64 + c], run);
    }
}

// -------------------- pooling tail: counts via binary search on sorted batch ---------

__global__ __launch_bounds__(64) void k_div_bs(const float* __restrict__ pool,
                                               const int* __restrict__ batch,
                                               float* __restrict__ out, int n) {
    int t = blockIdx.x * 64 + threadIdx.x;  // 64 blocks x 64 threads = 4096
    int g = t >> 6;
    // lower_bound(g) via binary search on sorted batch
    int lo = 0, hi = n;
    while (lo < hi) { int m = (lo + hi) >> 1; if (batch[m] < g) lo = m + 1; else hi = m; }
    int lb = lo;
    // upper_bound(g)
    lo = lb; hi = n;
    while (lo < hi) { int m = (lo + hi) >> 1; if (batch[m] <= g) lo = m + 1; else hi = m; }
    float c = (float)(lo - lb);
    c = c > 1.f ? c : 1.f;
    out[t] = pool[t] / c;
}

// -------------------- launch --------------------

extern "C" void kernel_launch(void* const* d_in, const int* in_sizes, int n_in,
                              void* d_out, int out_size, void* d_ws, size_t ws_size,
                              hipStream_t stream) {
    const float* x = (const float*)d_in[0];
    const int* edge = (const int*)d_in[1];
    const int* batch = (const int*)d_in[2];
    const float* W1 = (const float*)d_in[3];
    const float* b1 = (const float*)d_in[4];
    const float* W2 = (const float*)d_in[5];
    const float* b2 = (const float*)d_in[6];

    const int n = in_sizes[0] / 128;
    const int E = in_sizes[1] / 2;
    const int* src = edge;
    const int* dst = edge + E;

    // workspace layout
    size_t nA = ((size_t)n + 255) & ~(size_t)255;
    float* dinv = (float*)d_ws;                 // n
    int* cnt = (int*)(dinv + nA);               // n
    int* rowptr = cnt + nA;                     // n
    int* cursor = rowptr + nA;                  // n
    int* bsum = cursor + nA;                    // 1024
    float* pool = (float*)(bsum + 1024);        // 4096 (+pad)
    float* bufG = pool + 4096 + 256;            // n*128
    float* bufH = bufG + (size_t)n * 128;       // n*128
    int* csr = (int*)(bufH + (size_t)n * 128);  // E

    hipMemsetAsync(cnt, 0, (size_t)n * 4, stream);
    hipMemsetAsync(pool, 0, 4096 * 4, stream);

    // CSR build + dinv
    k_hist<<<(E + 255) / 256, 256, 0, stream>>>(dst, cnt, E);
    k_dinv<<<(n + 255) / 256, 256, 0, stream>>>(cnt, dinv, n);
    int nb = (n + 1023) / 1024;
    k_scan_block<<<nb, 256, 0, stream>>>(cnt, rowptr, bsum, n);
    k_scan_sums<<<1, 256, 0, stream>>>(bsum, nb);
    k_scan_add<<<nb, 256, 0, stream>>>(rowptr, bsum, n);
    hipMemcpyAsync(cursor, rowptr, (size_t)n * 4, hipMemcpyDeviceToDevice, stream);
    k_fill<<<(E + 255) / 256, 256, 0, stream>>>(src, dst, cursor, csr, E);

    // layer 1: GEMM (scaled) -> gather-aggregate (+self, relu, bias)
    k_gemm_scaled<128><<<(n + 15) / 16, 256, 0, stream>>>(x, W1, dinv, bufG, n);
    k_gather128<<<(n + 7) / 8, 256, 0, stream>>>(rowptr, cursor, csr, bufG, dinv, b1,
                                                 bufH, n);

    // layer 2: GEMM (scaled) -> gather-aggregate fused with pool
    k_gemm_scaled<64><<<(n + 15) / 16, 256, 0, stream>>>(bufH, W2, dinv, bufG, n);
    k_gather64_pool<<<(n + 15) / 16, 256, 0, stream>>>(rowptr, cursor, csr, bufG, dinv,
                                                       b2, batch, pool, n);

    // mean (counts via binary search on sorted batch — no atomics)
    k_div_bs<<<64, 64, 0, stream>>>(pool, batch, (float*)d_out, n);
}

// Round 4
// 509.885 us; speedup vs baseline: 10.0106x; 1.1470x over previous
//
#include <hip/hip_runtime.h>

// -------------------- degree / dinv --------------------

__global__ __launch_bounds__(256) void k_hist(const int* __restrict__ dst,
                                              int* __restrict__ cnt, int E) {
    int e = blockIdx.x * 256 + threadIdx.x;
    if (e < E) atomicAdd(&cnt[dst[e]], 1);
}

__global__ __launch_bounds__(256) void k_dinv(const int* __restrict__ cnt,
                                              float* __restrict__ dinv, int n) {
    int i = blockIdx.x * 256 + threadIdx.x;
    if (i < n) dinv[i] = rsqrtf((float)cnt[i] + 1.0f);  // +1 = self-loop
}

// -------------------- prefix scan (3-kernel, 1024 elems/block) --------------------

__global__ __launch_bounds__(256) void k_scan_block(const int* __restrict__ cnt,
                                                    int* __restrict__ excl,
                                                    int* __restrict__ bsum, int n) {
    __shared__ int lds[256];
    const int t = threadIdx.x;
    const int base = blockIdx.x * 1024 + t * 4;
    int v0 = 0, v1 = 0, v2 = 0, v3 = 0;
    if (base + 0 < n) v0 = cnt[base + 0];
    if (base + 1 < n) v1 = cnt[base + 1];
    if (base + 2 < n) v2 = cnt[base + 2];
    if (base + 3 < n) v3 = cnt[base + 3];
    int s = v0 + v1 + v2 + v3;
    lds[t] = s;
    __syncthreads();
    for (int off = 1; off < 256; off <<= 1) {
        int x = (t >= off) ? lds[t - off] : 0;
        __syncthreads();
        lds[t] += x;
        __syncthreads();
    }
    int run = lds[t] - s;
    if (t == 255) bsum[blockIdx.x] = lds[255];
    if (base + 0 < n) excl[base + 0] = run; run += v0;
    if (base + 1 < n) excl[base + 1] = run; run += v1;
    if (base + 2 < n) excl[base + 2] = run; run += v2;
    if (base + 3 < n) excl[base + 3] = run;
}

__global__ __launch_bounds__(256) void k_scan_sums(int* __restrict__ bsum, int nb) {
    __shared__ int lds[256];
    const int t = threadIdx.x;
    const int base = t * 4;
    int v0 = 0, v1 = 0, v2 = 0, v3 = 0;
    if (base + 0 < nb) v0 = bsum[base + 0];
    if (base + 1 < nb) v1 = bsum[base + 1];
    if (base + 2 < nb) v2 = bsum[base + 2];
    if (base + 3 < nb) v3 = bsum[base + 3];
    int s = v0 + v1 + v2 + v3;
    lds[t] = s;
    __syncthreads();
    for (int off = 1; off < 256; off <<= 1) {
        int x = (t >= off) ? lds[t - off] : 0;
        __syncthreads();
        lds[t] += x;
        __syncthreads();
    }
    int run = lds[t] - s;
    if (base + 0 < nb) bsum[base + 0] = run; run += v0;
    if (base + 1 < nb) bsum[base + 1] = run; run += v1;
    if (base + 2 < nb) bsum[base + 2] = run; run += v2;
    if (base + 3 < nb) bsum[base + 3] = run;
}

__global__ __launch_bounds__(256) void k_scan_add(int* __restrict__ excl,
                                                  const int* __restrict__ bsum, int n) {
    const int base = blockIdx.x * 1024 + threadIdx.x * 4;
    const int o = bsum[blockIdx.x];
    if (base + 0 < n) excl[base + 0] += o;
    if (base + 1 < n) excl[base + 1] += o;
    if (base + 2 < n) excl[base + 2] += o;
    if (base + 3 < n) excl[base + 3] += o;
}

// csr[cursor[dst]++] = src ; after this kernel cursor[i] == row end
__global__ __launch_bounds__(256) void k_fill(const int* __restrict__ src,
                                              const int* __restrict__ dst,
                                              int* __restrict__ cursor,
                                              int* __restrict__ csr, int E) {
    int e = blockIdx.x * 256 + threadIdx.x;
    if (e < E) {
        int p = atomicAdd(&cursor[dst[e]], 1);
        csr[p] = src[e];
    }
}

// -------- register-blocked GEMM: G[i][c] = dinv[i] * sum_k X[i][k]*W[k][c] ----------
// Per thread: 4 rows x 4 cols outer product. Per 4-k step: 8 ds_read_b128, 64 FMAs.

template <int BM, int D_OUT, int XPAD>
__global__ __launch_bounds__(256) void k_gemm_rb(const float* __restrict__ X,
                                                 const float* __restrict__ W,
                                                 const float* __restrict__ dinv,
                                                 float* __restrict__ G, int n) {
    constexpr int D_IN = 128;
    constexpr int XS = D_IN + XPAD;       // padded row stride (floats, multiple of 4)
    constexpr int CG = D_OUT / 4;         // threads along cols
    constexpr int RG = 256 / CG;          // row groups
    constexpr int RPT = BM / RG;          // rows per thread (=4)
    static_assert(RPT == 4, "layout assumes 4 rows/thread");

    __shared__ float Ws[D_IN * D_OUT];
    __shared__ float Xs[BM * XS];

    const int tid = threadIdx.x;
    const int row0blk = blockIdx.x * BM;

    for (int idx = tid * 4; idx < D_IN * D_OUT; idx += 1024)
        *(float4*)&Ws[idx] = *(const float4*)&W[idx];
    for (int idx = tid * 4; idx < BM * D_IN; idx += 1024) {
        int r = idx >> 7, k = idx & 127;
        int gr = row0blk + r;
        float4 v = make_float4(0.f, 0.f, 0.f, 0.f);
        if (gr < n) v = *(const float4*)&X[(size_t)gr * D_IN + k];
        *(float4*)&Xs[r * XS + k] = v;
    }
    __syncthreads();

    const int cg = tid % CG;   // cols cg*4 .. cg*4+3
    const int rg = tid / CG;   // rows rg*4 .. rg*4+3
    const float4* Ws4 = (const float4*)Ws;

    float4 acc[4];
#pragma unroll
    for (int r = 0; r < 4; r++) acc[r] = make_float4(0.f, 0.f, 0.f, 0.f);

#pragma unroll 2
    for (int k = 0; k < D_IN; k += 4) {
        float4 w0 = Ws4[(k + 0) * CG + cg];
        float4 w1 = Ws4[(k + 1) * CG + cg];
        float4 w2 = Ws4[(k + 2) * CG + cg];
        float4 w3 = Ws4[(k + 3) * CG + cg];
#pragma unroll
        for (int r = 0; r < 4; r++) {
            float4 xv = *(const float4*)&Xs[(rg * 4 + r) * XS + k];
            acc[r].x += xv.x * w0.x + xv.y * w1.x + xv.z * w2.x + xv.w * w3.x;
            acc[r].y += xv.x * w0.y + xv.y * w1.y + xv.z * w2.y + xv.w * w3.y;
            acc[r].z += xv.x * w0.z + xv.y * w1.z + xv.z * w2.z + xv.w * w3.z;
            acc[r].w += xv.x * w0.w + xv.y * w1.w + xv.z * w2.w + xv.w * w3.w;
        }
    }

#pragma unroll
    for (int r = 0; r < 4; r++) {
        int gr = row0blk + rg * 4 + r;
        if (gr < n) {
            float s = dinv[gr];
            float4 o;
            o.x = s * acc[r].x; o.y = s * acc[r].y;
            o.z = s * acc[r].z; o.w = s * acc[r].w;
            *(float4*)&G[(size_t)gr * D_OUT + cg * 4] = o;
        }
    }
}

// -------------------- layer-1 aggregation: 32 lanes per dst row --------------------

__global__ __launch_bounds__(256) void k_gather128(const int* __restrict__ rowptr,
                                                   const int* __restrict__ rowend,
                                                   const int* __restrict__ csr,
                                                   const float* __restrict__ G,
                                                   const float* __restrict__ dinv,
                                                   const float* __restrict__ b,
                                                   float* __restrict__ H, int n) {
    const int g = blockIdx.x * 8 + threadIdx.x / 32;
    const int lane = threadIdx.x & 31;
    if (g >= n) return;
    const int beg = rowptr[g], end = rowend[g];
    float4 acc = *(const float4*)&G[(size_t)g * 128 + lane * 4];  // self-loop term
    int e = beg;
    for (; e + 1 < end; e += 2) {
        int s0 = csr[e], s1 = csr[e + 1];
        float4 a = *(const float4*)&G[(size_t)s0 * 128 + lane * 4];
        float4 c2 = *(const float4*)&G[(size_t)s1 * 128 + lane * 4];
        acc.x += a.x + c2.x; acc.y += a.y + c2.y;
        acc.z += a.z + c2.z; acc.w += a.w + c2.w;
    }
    if (e < end) {
        int s0 = csr[e];
        float4 a = *(const float4*)&G[(size_t)s0 * 128 + lane * 4];
        acc.x += a.x; acc.y += a.y; acc.z += a.z; acc.w += a.w;
    }
    const float di = dinv[g];
    float4 bb = *(const float4*)&b[lane * 4];
    float4 o;
    o.x = fmaxf(di * acc.x + bb.x, 0.f);
    o.y = fmaxf(di * acc.y + bb.y, 0.f);
    o.z = fmaxf(di * acc.z + bb.z, 0.f);
    o.w = fmaxf(di * acc.w + bb.w, 0.f);
    *(float4*)&H[(size_t)g * 128 + lane * 4] = o;
}

// -------------------- layer-2 aggregation fused with mean-pool accumulate ------------

__global__ __launch_bounds__(256) void k_gather64_pool(const int* __restrict__ rowptr,
                                                       const int* __restrict__ rowend,
                                                       const int* __restrict__ csr,
                                                       const float* __restrict__ G,
                                                       const float* __restrict__ dinv,
                                                       const float* __restrict__ b,
                                                       const int* __restrict__ batch,
                                                       float* __restrict__ pool, int n) {
    __shared__ float po[16][68];
    __shared__ int pg[16];
    const int grp = threadIdx.x / 16;
    const int lane = threadIdx.x & 15;
    const int g = blockIdx.x * 16 + grp;

    float4 o = make_float4(0.f, 0.f, 0.f, 0.f);
    if (g < n) {
        const int beg = rowptr[g], end = rowend[g];
        float4 acc = *(const float4*)&G[(size_t)g * 64 + lane * 4];
        int e = beg;
        for (; e + 1 < end; e += 2) {
            int s0 = csr[e], s1 = csr[e + 1];
            float4 a = *(const float4*)&G[(size_t)s0 * 64 + lane * 4];
            float4 c2 = *(const float4*)&G[(size_t)s1 * 64 + lane * 4];
            acc.x += a.x + c2.x; acc.y += a.y + c2.y;
            acc.z += a.z + c2.z; acc.w += a.w + c2.w;
        }
        if (e < end) {
            int s0 = csr[e];
            float4 a = *(const float4*)&G[(size_t)s0 * 64 + lane * 4];
            acc.x += a.x; acc.y += a.y; acc.z += a.z; acc.w += a.w;
        }
        const float di = dinv[g];
        float4 bb = *(const float4*)&b[lane * 4];
        o.x = fmaxf(di * acc.x + bb.x, 0.f);
        o.y = fmaxf(di * acc.y + bb.y, 0.f);
        o.z = fmaxf(di * acc.z + bb.z, 0.f);
        o.w = fmaxf(di * acc.w + bb.w, 0.f);
    }
    if (lane == 0) pg[grp] = (g < n) ? batch[g] : -1;
    *(float4*)&po[grp][lane * 4] = o;
    __syncthreads();

    if (threadIdx.x < 64) {
        const int c = threadIdx.x;
        float run = 0.f;
        int cur = -1;
        for (int r = 0; r < 16; r++) {
            int gr = pg[r];
            if (gr < 0) continue;
            if (gr != cur) {
                if (cur >= 0) atomicAdd(&pool[cur * 64 + c], run);
                cur = gr;
                run = 0.f;
            }
            run += po[r][c];
        }
        if (cur >= 0) atomicAdd(&pool[cur * 64 + c], run);
    }
}

// -------------------- pooling tail: counts via binary search on sorted batch ---------

__global__ __launch_bounds__(64) void k_div_bs(const float* __restrict__ pool,
                                               const int* __restrict__ batch,
                                               float* __restrict__ out, int n) {
    int t = blockIdx.x * 64 + threadIdx.x;
    int g = t >> 6;
    int lo = 0, hi = n;
    while (lo < hi) { int m = (lo + hi) >> 1; if (batch[m] < g) lo = m + 1; else hi = m; }
    int lb = lo;
    lo = lb; hi = n;
    while (lo < hi) { int m = (lo + hi) >> 1; if (batch[m] <= g) lo = m + 1; else hi = m; }
    float c = (float)(lo - lb);
    c = c > 1.f ? c : 1.f;
    out[t] = pool[t] / c;
}

// -------------------- launch --------------------

extern "C" void kernel_launch(void* const* d_in, const int* in_sizes, int n_in,
                              void* d_out, int out_size, void* d_ws, size_t ws_size,
                              hipStream_t stream) {
    const float* x = (const float*)d_in[0];
    const int* edge = (const int*)d_in[1];
    const int* batch = (const int*)d_in[2];
    const float* W1 = (const float*)d_in[3];
    const float* b1 = (const float*)d_in[4];
    const float* W2 = (const float*)d_in[5];
    const float* b2 = (const float*)d_in[6];

    const int n = in_sizes[0] / 128;
    const int E = in_sizes[1] / 2;
    const int* src = edge;
    const int* dst = edge + E;

    size_t nA = ((size_t)n + 255) & ~(size_t)255;
    float* dinv = (float*)d_ws;                 // n
    int* cnt = (int*)(dinv + nA);               // n
    int* rowptr = cnt + nA;                     // n
    int* cursor = rowptr + nA;                  // n
    int* bsum = cursor + nA;                    // 1024
    float* pool = (float*)(bsum + 1024);        // 4096 (+pad)
    float* bufG = pool + 4096 + 256;            // n*128
    float* bufH = bufG + (size_t)n * 128;       // n*128
    int* csr = (int*)(bufH + (size_t)n * 128);  // E

    hipMemsetAsync(cnt, 0, (size_t)n * 4, stream);
    hipMemsetAsync(pool, 0, 4096 * 4, stream);

    // CSR build + dinv
    k_hist<<<(E + 255) / 256, 256, 0, stream>>>(dst, cnt, E);
    k_dinv<<<(n + 255) / 256, 256, 0, stream>>>(cnt, dinv, n);
    int nb = (n + 1023) / 1024;
    k_scan_block<<<nb, 256, 0, stream>>>(cnt, rowptr, bsum, n);
    k_scan_sums<<<1, 256, 0, stream>>>(bsum, nb);
    k_scan_add<<<nb, 256, 0, stream>>>(rowptr, bsum, n);
    hipMemcpyAsync(cursor, rowptr, (size_t)n * 4, hipMemcpyDeviceToDevice, stream);
    k_fill<<<(E + 255) / 256, 256, 0, stream>>>(src, dst, cursor, csr, E);

    // layer 1: GEMM (scaled) -> gather-aggregate (+self, relu, bias)
    k_gemm_rb<32, 128, 0><<<(n + 31) / 32, 256, 0, stream>>>(x, W1, dinv, bufG, n);
    k_gather128<<<(n + 7) / 8, 256, 0, stream>>>(rowptr, cursor, csr, bufG, dinv, b1,
                                                 bufH, n);

    // layer 2: GEMM (scaled) -> gather-aggregate fused with pool
    k_gemm_rb<64, 64, 4><<<(n + 63) / 64, 256, 0, stream>>>(bufH, W2, dinv, bufG, n);
    k_gather64_pool<<<(n + 15) / 16, 256, 0, stream>>>(rowptr, cursor, csr, bufG, dinv,
                                                       b2, batch, pool, n);

    // mean (counts via binary search on sorted batch — no atomics)
    k_div_bs<<<64, 64, 0, stream>>>(pool, batch, (float*)d_out, n);
}

// Round 5
// 362.368 us; speedup vs baseline: 14.0859x; 1.4071x over previous
//
#include <hip/hip_runtime.h>

// ============ bucketed CSR build (bucket = dst >> 8, <=512 buckets) ============

#define BSH 8
#define NBMAX 512
#define EPB 4096  // edges per block in bhist/bscatter

__global__ __launch_bounds__(256) void k_bhist(const int* __restrict__ dst,
                                               int* __restrict__ bcnt, int E, int nb) {
    __shared__ int h[NBMAX];
    const int tid = threadIdx.x;
    for (int i = tid; i < NBMAX; i += 256) h[i] = 0;
    __syncthreads();
    const int e0 = blockIdx.x * EPB;
    for (int i = tid; i < EPB; i += 256) {
        int e = e0 + i;
        if (e < E) atomicAdd(&h[dst[e] >> BSH], 1);
    }
    __syncthreads();
    for (int i = tid; i < nb; i += 256)
        if (h[i]) atomicAdd(&bcnt[i], h[i]);
}

__global__ __launch_bounds__(512) void k_bscan(const int* __restrict__ bcnt,
                                               int* __restrict__ boff,
                                               int* __restrict__ bcur, int nb) {
    __shared__ int a[NBMAX];
    const int t = threadIdx.x;
    int v = (t < nb) ? bcnt[t] : 0;
    a[t] = v;
    __syncthreads();
    for (int off = 1; off < NBMAX; off <<= 1) {
        int x = (t >= off) ? a[t - off] : 0;
        __syncthreads();
        a[t] += x;
        __syncthreads();
    }
    if (t < nb) {
        int excl = a[t] - v;
        boff[t] = excl;
        bcur[t] = excl;
    }
}

// scatter (src,dst) pairs into bucket-segmented regions, per-block contiguous runs
__global__ __launch_bounds__(256) void k_bscatter(const int* __restrict__ src,
                                                  const int* __restrict__ dst,
                                                  int* __restrict__ bcur,
                                                  int2* __restrict__ pairs, int E, int nb) {
    __shared__ int h[NBMAX];
    __shared__ int base[NBMAX];
    const int tid = threadIdx.x;
    for (int i = tid; i < NBMAX; i += 256) h[i] = 0;
    __syncthreads();
    const int e0 = blockIdx.x * EPB;
    for (int i = tid; i < EPB; i += 256) {
        int e = e0 + i;
        if (e < E) atomicAdd(&h[dst[e] >> BSH], 1);
    }
    __syncthreads();
    for (int b = tid; b < nb; b += 256) {
        int c = h[b];
        base[b] = c ? atomicAdd(&bcur[b], c) : 0;
        h[b] = 0;  // reuse as local cursor
    }
    __syncthreads();
    for (int i = tid; i < EPB; i += 256) {
        int e = e0 + i;
        if (e < E) {
            int s = src[e], d = dst[e];
            int bk = d >> BSH;
            int off = atomicAdd(&h[bk], 1);
            pairs[base[bk] + off] = make_int2(s, d);
        }
    }
}

// per-bucket: degree, local scan -> rowptr/rowend/dinv, local-cursor csr fill
__global__ __launch_bounds__(256) void k_bcsr(const int2* __restrict__ pairs,
                                              const int* __restrict__ boff,
                                              const int* __restrict__ bcurEnd,
                                              int* __restrict__ rowptr,
                                              int* __restrict__ rowend,
                                              float* __restrict__ dinv,
                                              int* __restrict__ csr, int n) {
    __shared__ int deg[256], sc[256], cur[256];
    const int t = threadIdx.x;
    const int b = blockIdx.x;
    const int beg = boff[b], end = bcurEnd[b];
    deg[t] = 0;
    __syncthreads();
    for (int i = beg + t; i < end; i += 256) {
        int2 p = pairs[i];
        atomicAdd(&deg[p.y & 255], 1);
    }
    __syncthreads();
    int dv = deg[t];
    sc[t] = dv;
    __syncthreads();
    for (int off = 1; off < 256; off <<= 1) {
        int x = (t >= off) ? sc[t - off] : 0;
        __syncthreads();
        sc[t] += x;
        __syncthreads();
    }
    int excl = sc[t] - dv;
    cur[t] = excl;
    int d = (b << BSH) + t;
    if (d < n) {
        int r = beg + excl;
        rowptr[d] = r;
        rowend[d] = r + dv;
        dinv[d] = rsqrtf((float)dv + 1.0f);  // +1 self-loop
    }
    __syncthreads();
    for (int i = beg + t; i < end; i += 256) {
        int2 p = pairs[i];
        int off = atomicAdd(&cur[p.y & 255], 1);
        csr[beg + off] = p.x;
    }
}

// -------- register-blocked GEMM: G[i][c] = dinv[i] * sum_k X[i][k]*W[k][c] ----------

template <int BM, int D_OUT, int XPAD>
__global__ __launch_bounds__(256) void k_gemm_rb(const float* __restrict__ X,
                                                 const float* __restrict__ W,
                                                 const float* __restrict__ dinv,
                                                 float* __restrict__ G, int n) {
    constexpr int D_IN = 128;
    constexpr int XS = D_IN + XPAD;
    constexpr int CG = D_OUT / 4;
    constexpr int RG = 256 / CG;
    constexpr int RPT = BM / RG;
    static_assert(RPT == 4, "layout assumes 4 rows/thread");

    __shared__ float Ws[D_IN * D_OUT];
    __shared__ float Xs[BM * XS];

    const int tid = threadIdx.x;
    const int row0blk = blockIdx.x * BM;

    for (int idx = tid * 4; idx < D_IN * D_OUT; idx += 1024)
        *(float4*)&Ws[idx] = *(const float4*)&W[idx];
    for (int idx = tid * 4; idx < BM * D_IN; idx += 1024) {
        int r = idx >> 7, k = idx & 127;
        int gr = row0blk + r;
        float4 v = make_float4(0.f, 0.f, 0.f, 0.f);
        if (gr < n) v = *(const float4*)&X[(size_t)gr * D_IN + k];
        *(float4*)&Xs[r * XS + k] = v;
    }
    __syncthreads();

    const int cg = tid % CG;
    const int rg = tid / CG;
    const float4* Ws4 = (const float4*)Ws;

    float4 acc[4];
#pragma unroll
    for (int r = 0; r < 4; r++) acc[r] = make_float4(0.f, 0.f, 0.f, 0.f);

#pragma unroll 2
    for (int k = 0; k < D_IN; k += 4) {
        float4 w0 = Ws4[(k + 0) * CG + cg];
        float4 w1 = Ws4[(k + 1) * CG + cg];
        float4 w2 = Ws4[(k + 2) * CG + cg];
        float4 w3 = Ws4[(k + 3) * CG + cg];
#pragma unroll
        for (int r = 0; r < 4; r++) {
            float4 xv = *(const float4*)&Xs[(rg * 4 + r) * XS + k];
            acc[r].x += xv.x * w0.x + xv.y * w1.x + xv.z * w2.x + xv.w * w3.x;
            acc[r].y += xv.x * w0.y + xv.y * w1.y + xv.z * w2.y + xv.w * w3.y;
            acc[r].z += xv.x * w0.z + xv.y * w1.z + xv.z * w2.z + xv.w * w3.z;
            acc[r].w += xv.x * w0.w + xv.y * w1.w + xv.z * w2.w + xv.w * w3.w;
        }
    }

#pragma unroll
    for (int r = 0; r < 4; r++) {
        int gr = row0blk + rg * 4 + r;
        if (gr < n) {
            float s = dinv[gr];
            float4 o;
            o.x = s * acc[r].x; o.y = s * acc[r].y;
            o.z = s * acc[r].z; o.w = s * acc[r].w;
            *(float4*)&G[(size_t)gr * D_OUT + cg * 4] = o;
        }
    }
}

// -------------------- layer-1 aggregation: 32 lanes per dst row --------------------

__global__ __launch_bounds__(256) void k_gather128(const int* __restrict__ rowptr,
                                                   const int* __restrict__ rowend,
                                                   const int* __restrict__ csr,
                                                   const float* __restrict__ G,
                                                   const float* __restrict__ dinv,
                                                   const float* __restrict__ b,
                                                   float* __restrict__ H, int n) {
    const int g = blockIdx.x * 8 + threadIdx.x / 32;
    const int lane = threadIdx.x & 31;
    if (g >= n) return;
    const int beg = rowptr[g], end = rowend[g];
    float4 acc = *(const float4*)&G[(size_t)g * 128 + lane * 4];  // self-loop term
    int e = beg;
    for (; e + 1 < end; e += 2) {
        int s0 = csr[e], s1 = csr[e + 1];
        float4 a = *(const float4*)&G[(size_t)s0 * 128 + lane * 4];
        float4 c2 = *(const float4*)&G[(size_t)s1 * 128 + lane * 4];
        acc.x += a.x + c2.x; acc.y += a.y + c2.y;
        acc.z += a.z + c2.z; acc.w += a.w + c2.w;
    }
    if (e < end) {
        int s0 = csr[e];
        float4 a = *(const float4*)&G[(size_t)s0 * 128 + lane * 4];
        acc.x += a.x; acc.y += a.y; acc.z += a.z; acc.w += a.w;
    }
    const float di = dinv[g];
    float4 bb = *(const float4*)&b[lane * 4];
    float4 o;
    o.x = fmaxf(di * acc.x + bb.x, 0.f);
    o.y = fmaxf(di * acc.y + bb.y, 0.f);
    o.z = fmaxf(di * acc.z + bb.z, 0.f);
    o.w = fmaxf(di * acc.w + bb.w, 0.f);
    *(float4*)&H[(size_t)g * 128 + lane * 4] = o;
}

// -------------------- layer-2 aggregation fused with mean-pool accumulate ------------

__global__ __launch_bounds__(256) void k_gather64_pool(const int* __restrict__ rowptr,
                                                       const int* __restrict__ rowend,
                                                       const int* __restrict__ csr,
                                                       const float* __restrict__ G,
                                                       const float* __restrict__ dinv,
                                                       const float* __restrict__ b,
                                                       const int* __restrict__ batch,
                                                       float* __restrict__ pool, int n) {
    __shared__ float po[16][68];
    __shared__ int pg[16];
    const int grp = threadIdx.x / 16;
    const int lane = threadIdx.x & 15;
    const int g = blockIdx.x * 16 + grp;

    float4 o = make_float4(0.f, 0.f, 0.f, 0.f);
    if (g < n) {
        const int beg = rowptr[g], end = rowend[g];
        float4 acc = *(const float4*)&G[(size_t)g * 64 + lane * 4];
        int e = beg;
        for (; e + 1 < end; e += 2) {
            int s0 = csr[e], s1 = csr[e + 1];
            float4 a = *(const float4*)&G[(size_t)s0 * 64 + lane * 4];
            float4 c2 = *(const float4*)&G[(size_t)s1 * 64 + lane * 4];
            acc.x += a.x + c2.x; acc.y += a.y + c2.y;
            acc.z += a.z + c2.z; acc.w += a.w + c2.w;
        }
        if (e < end) {
            int s0 = csr[e];
            float4 a = *(const float4*)&G[(size_t)s0 * 64 + lane * 4];
            acc.x += a.x; acc.y += a.y; acc.z += a.z; acc.w += a.w;
        }
        const float di = dinv[g];
        float4 bb = *(const float4*)&b[lane * 4];
        o.x = fmaxf(di * acc.x + bb.x, 0.f);
        o.y = fmaxf(di * acc.y + bb.y, 0.f);
        o.z = fmaxf(di * acc.z + bb.z, 0.f);
        o.w = fmaxf(di * acc.w + bb.w, 0.f);
    }
    if (lane == 0) pg[grp] = (g < n) ? batch[g] : -1;
    *(float4*)&po[grp][lane * 4] = o;
    __syncthreads();

    if (threadIdx.x < 64) {
        const int c = threadIdx.x;
        float run = 0.f;
        int cur = -1;
        for (int r = 0; r < 16; r++) {
            int gr = pg[r];
            if (gr < 0) continue;
            if (gr != cur) {
                if (cur >= 0) atomicAdd(&pool[cur * 64 + c], run);
                cur = gr;
                run = 0.f;
            }
            run += po[r][c];
        }
        if (cur >= 0) atomicAdd(&pool[cur * 64 + c], run);
    }
}

// -------------------- pooling tail: counts via binary search on sorted batch ---------

__global__ __launch_bounds__(64) void k_div_bs(const float* __restrict__ pool,
                                               const int* __restrict__ batch,
                                               float* __restrict__ out, int n) {
    int t = blockIdx.x * 64 + threadIdx.x;
    int g = t >> 6;
    int lo = 0, hi = n;
    while (lo < hi) { int m = (lo + hi) >> 1; if (batch[m] < g) lo = m + 1; else hi = m; }
    int lb = lo;
    lo = lb; hi = n;
    while (lo < hi) { int m = (lo + hi) >> 1; if (batch[m] <= g) lo = m + 1; else hi = m; }
    float c = (float)(lo - lb);
    c = c > 1.f ? c : 1.f;
    out[t] = pool[t] / c;
}

// -------------------- launch --------------------

extern "C" void kernel_launch(void* const* d_in, const int* in_sizes, int n_in,
                              void* d_out, int out_size, void* d_ws, size_t ws_size,
                              hipStream_t stream) {
    const float* x = (const float*)d_in[0];
    const int* edge = (const int*)d_in[1];
    const int* batch = (const int*)d_in[2];
    const float* W1 = (const float*)d_in[3];
    const float* b1 = (const float*)d_in[4];
    const float* W2 = (const float*)d_in[5];
    const float* b2 = (const float*)d_in[6];

    const int n = in_sizes[0] / 128;
    const int E = in_sizes[1] / 2;
    const int* src = edge;
    const int* dst = edge + E;
    const int nb = (n + 255) >> BSH;  // buckets (<=512 for n<=131072)

    size_t nA = ((size_t)n + 255) & ~(size_t)255;
    float* dinv = (float*)d_ws;                 // nA
    int* rowptr = (int*)(dinv + nA);            // nA
    int* rowend = rowptr + nA;                  // nA
    int* bcnt = rowend + nA;                    // 512
    int* boff = bcnt + NBMAX;                   // 512
    int* bcur = boff + NBMAX;                   // 512
    float* pool = (float*)(bcur + NBMAX);       // 4096 (+pad)
    float* bufG = pool + 4096 + 256;            // n*128  (pairs aliases the front)
    float* bufH = bufG + (size_t)n * 128;       // n*128
    int* csr = (int*)(bufH + (size_t)n * 128);  // E
    int2* pairs = (int2*)bufG;                  // E pairs (dead before gemm1 writes bufG)

    hipMemsetAsync(bcnt, 0, NBMAX * 4, stream);
    hipMemsetAsync(pool, 0, 4096 * 4, stream);

    // bucketed CSR build (+ dinv)
    int gE = (E + EPB - 1) / EPB;
    k_bhist<<<gE, 256, 0, stream>>>(dst, bcnt, E, nb);
    k_bscan<<<1, NBMAX, 0, stream>>>(bcnt, boff, bcur, nb);
    k_bscatter<<<gE, 256, 0, stream>>>(src, dst, bcur, pairs, E, nb);
    k_bcsr<<<nb, 256, 0, stream>>>(pairs, boff, bcur, rowptr, rowend, dinv, csr, n);

    // layer 1: GEMM (scaled) -> gather-aggregate (+self, relu, bias)
    k_gemm_rb<32, 128, 0><<<(n + 31) / 32, 256, 0, stream>>>(x, W1, dinv, bufG, n);
    k_gather128<<<(n + 7) / 8, 256, 0, stream>>>(rowptr, rowend, csr, bufG, dinv, b1,
                                                 bufH, n);

    // layer 2: GEMM (scaled) -> gather-aggregate fused with pool
    k_gemm_rb<64, 64, 4><<<(n + 63) / 64, 256, 0, stream>>>(bufH, W2, dinv, bufG, n);
    k_gather64_pool<<<(n + 15) / 16, 256, 0, stream>>>(rowptr, rowend, csr, bufG, dinv,
                                                       b2, batch, pool, n);

    // mean (counts via binary search on sorted batch — no atomics)
    k_div_bs<<<64, 64, 0, stream>>>(pool, batch, (float*)d_out, n);
}

// Round 6
// 291.248 us; speedup vs baseline: 17.5255x; 1.2442x over previous
//
#include <hip/hip_runtime.h>

typedef unsigned short ushort_t;
typedef unsigned int uint_t;

__device__ inline ushort_t bf16_rne(float f) {
    uint_t u = __float_as_uint(f);
    return (ushort_t)((u + 0x7FFFu + ((u >> 16) & 1u)) >> 16);
}

__device__ inline float4 bf4_to_f4(uint2 v) {
    float4 f;
    f.x = __uint_as_float(v.x << 16);
    f.y = __uint_as_float(v.x & 0xFFFF0000u);
    f.z = __uint_as_float(v.y << 16);
    f.w = __uint_as_float(v.y & 0xFFFF0000u);
    return f;
}

// ============ bucketed CSR build (bucket = dst >> 8, <=512 buckets) ============

#define BSH 8
#define NBMAX 512
#define EPB 4096

__global__ __launch_bounds__(256) void k_bhist(const int* __restrict__ dst,
                                               int* __restrict__ bcnt, int E, int nb) {
    __shared__ int h[NBMAX];
    const int tid = threadIdx.x;
    for (int i = tid; i < NBMAX; i += 256) h[i] = 0;
    __syncthreads();
    const int e0 = blockIdx.x * EPB;
    for (int i = tid; i < EPB; i += 256) {
        int e = e0 + i;
        if (e < E) atomicAdd(&h[dst[e] >> BSH], 1);
    }
    __syncthreads();
    for (int i = tid; i < nb; i += 256)
        if (h[i]) atomicAdd(&bcnt[i], h[i]);
}

__global__ __launch_bounds__(512) void k_bscan(const int* __restrict__ bcnt,
                                               int* __restrict__ boff,
                                               int* __restrict__ bcur, int nb) {
    __shared__ int a[NBMAX];
    const int t = threadIdx.x;
    int v = (t < nb) ? bcnt[t] : 0;
    a[t] = v;
    __syncthreads();
    for (int off = 1; off < NBMAX; off <<= 1) {
        int x = (t >= off) ? a[t - off] : 0;
        __syncthreads();
        a[t] += x;
        __syncthreads();
    }
    if (t < nb) {
        int excl = a[t] - v;
        boff[t] = excl;
        bcur[t] = excl;
    }
}

__global__ __launch_bounds__(256) void k_bscatter(const int* __restrict__ src,
                                                  const int* __restrict__ dst,
                                                  int* __restrict__ bcur,
                                                  int2* __restrict__ pairs, int E, int nb) {
    __shared__ int h[NBMAX];
    __shared__ int base[NBMAX];
    const int tid = threadIdx.x;
    for (int i = tid; i < NBMAX; i += 256) h[i] = 0;
    __syncthreads();
    const int e0 = blockIdx.x * EPB;
    for (int i = tid; i < EPB; i += 256) {
        int e = e0 + i;
        if (e < E) atomicAdd(&h[dst[e] >> BSH], 1);
    }
    __syncthreads();
    for (int b = tid; b < nb; b += 256) {
        int c = h[b];
        base[b] = c ? atomicAdd(&bcur[b], c) : 0;
        h[b] = 0;
    }
    __syncthreads();
    for (int i = tid; i < EPB; i += 256) {
        int e = e0 + i;
        if (e < E) {
            int s = src[e], d = dst[e];
            int bk = d >> BSH;
            int off = atomicAdd(&h[bk], 1);
            pairs[base[bk] + off] = make_int2(s, d);
        }
    }
}

__global__ __launch_bounds__(256) void k_bcsr(const int2* __restrict__ pairs,
                                              const int* __restrict__ boff,
                                              const int* __restrict__ bcurEnd,
                                              int* __restrict__ rowptr,
                                              int* __restrict__ rowend,
                                              float* __restrict__ dinv,
                                              int* __restrict__ csr, int n) {
    __shared__ int deg[256], sc[256], cur[256];
    const int t = threadIdx.x;
    const int b = blockIdx.x;
    const int beg = boff[b], end = bcurEnd[b];
    deg[t] = 0;
    __syncthreads();
    for (int i = beg + t; i < end; i += 256) {
        int2 p = pairs[i];
        atomicAdd(&deg[p.y & 255], 1);
    }
    __syncthreads();
    int dv = deg[t];
    sc[t] = dv;
    __syncthreads();
    for (int off = 1; off < 256; off <<= 1) {
        int x = (t >= off) ? sc[t - off] : 0;
        __syncthreads();
        sc[t] += x;
        __syncthreads();
    }
    int excl = sc[t] - dv;
    cur[t] = excl;
    int d = (b << BSH) + t;
    if (d < n) {
        int r = beg + excl;
        rowptr[d] = r;
        rowend[d] = r + dv;
        dinv[d] = rsqrtf((float)dv + 1.0f);
    }
    __syncthreads();
    for (int i = beg + t; i < end; i += 256) {
        int2 p = pairs[i];
        int off = atomicAdd(&cur[p.y & 255], 1);
        csr[beg + off] = p.x;
    }
}

// -------- register-blocked GEMM, bf16 output: G[i][c] = bf16(dinv[i]*sum X W) --------

template <int BM, int D_OUT, int XPAD>
__global__ __launch_bounds__(256) void k_gemm_rb_bf(const float* __restrict__ X,
                                                    const float* __restrict__ W,
                                                    const float* __restrict__ dinv,
                                                    ushort_t* __restrict__ G, int n) {
    constexpr int D_IN = 128;
    constexpr int XS = D_IN + XPAD;
    constexpr int CG = D_OUT / 4;
    constexpr int RG = 256 / CG;
    constexpr int RPT = BM / RG;
    static_assert(RPT == 4, "layout assumes 4 rows/thread");

    __shared__ float Ws[D_IN * D_OUT];
    __shared__ float Xs[BM * XS];

    const int tid = threadIdx.x;
    const int row0blk = blockIdx.x * BM;

    for (int idx = tid * 4; idx < D_IN * D_OUT; idx += 1024)
        *(float4*)&Ws[idx] = *(const float4*)&W[idx];
    for (int idx = tid * 4; idx < BM * D_IN; idx += 1024) {
        int r = idx >> 7, k = idx & 127;
        int gr = row0blk + r;
        float4 v = make_float4(0.f, 0.f, 0.f, 0.f);
        if (gr < n) v = *(const float4*)&X[(size_t)gr * D_IN + k];
        *(float4*)&Xs[r * XS + k] = v;
    }
    __syncthreads();

    const int cg = tid % CG;
    const int rg = tid / CG;
    const float4* Ws4 = (const float4*)Ws;

    float4 acc[4];
#pragma unroll
    for (int r = 0; r < 4; r++) acc[r] = make_float4(0.f, 0.f, 0.f, 0.f);

#pragma unroll 2
    for (int k = 0; k < D_IN; k += 4) {
        float4 w0 = Ws4[(k + 0) * CG + cg];
        float4 w1 = Ws4[(k + 1) * CG + cg];
        float4 w2 = Ws4[(k + 2) * CG + cg];
        float4 w3 = Ws4[(k + 3) * CG + cg];
#pragma unroll
        for (int r = 0; r < 4; r++) {
            float4 xv = *(const float4*)&Xs[(rg * 4 + r) * XS + k];
            acc[r].x += xv.x * w0.x + xv.y * w1.x + xv.z * w2.x + xv.w * w3.x;
            acc[r].y += xv.x * w0.y + xv.y * w1.y + xv.z * w2.y + xv.w * w3.y;
            acc[r].z += xv.x * w0.z + xv.y * w1.z + xv.z * w2.z + xv.w * w3.z;
            acc[r].w += xv.x * w0.w + xv.y * w1.w + xv.z * w2.w + xv.w * w3.w;
        }
    }

#pragma unroll
    for (int r = 0; r < 4; r++) {
        int gr = row0blk + rg * 4 + r;
        if (gr < n) {
            float s = dinv[gr];
            ushort4 o;
            o.x = bf16_rne(s * acc[r].x);
            o.y = bf16_rne(s * acc[r].y);
            o.z = bf16_rne(s * acc[r].z);
            o.w = bf16_rne(s * acc[r].w);
            *(ushort4*)&G[(size_t)gr * D_OUT + cg * 4] = o;
        }
    }
}

// ------------- layer-1 aggregation: 32 lanes/row, bf16 G, 4-way unroll -------------

__global__ __launch_bounds__(256) void k_gather128(const int* __restrict__ rowptr,
                                                   const int* __restrict__ rowend,
                                                   const int* __restrict__ csr,
                                                   const ushort_t* __restrict__ G,
                                                   const float* __restrict__ dinv,
                                                   const float* __restrict__ b,
                                                   float* __restrict__ H, int n) {
    const int g = blockIdx.x * 8 + threadIdx.x / 32;
    const int lane = threadIdx.x & 31;
    if (g >= n) return;
    const int beg = rowptr[g], end = rowend[g];

    float4 acc = bf4_to_f4(*(const uint2*)&G[(size_t)g * 128 + lane * 4]);  // self
    int e = beg;
    for (; e + 3 < end; e += 4) {
        int s0 = csr[e], s1 = csr[e + 1], s2 = csr[e + 2], s3 = csr[e + 3];
        uint2 r0 = *(const uint2*)&G[(size_t)s0 * 128 + lane * 4];
        uint2 r1 = *(const uint2*)&G[(size_t)s1 * 128 + lane * 4];
        uint2 r2 = *(const uint2*)&G[(size_t)s2 * 128 + lane * 4];
        uint2 r3 = *(const uint2*)&G[(size_t)s3 * 128 + lane * 4];
        float4 a0 = bf4_to_f4(r0), a1 = bf4_to_f4(r1);
        float4 a2 = bf4_to_f4(r2), a3 = bf4_to_f4(r3);
        acc.x += (a0.x + a1.x) + (a2.x + a3.x);
        acc.y += (a0.y + a1.y) + (a2.y + a3.y);
        acc.z += (a0.z + a1.z) + (a2.z + a3.z);
        acc.w += (a0.w + a1.w) + (a2.w + a3.w);
    }
    for (; e < end; e++) {
        int s0 = csr[e];
        float4 a = bf4_to_f4(*(const uint2*)&G[(size_t)s0 * 128 + lane * 4]);
        acc.x += a.x; acc.y += a.y; acc.z += a.z; acc.w += a.w;
    }
    const float di = dinv[g];
    float4 bb = *(const float4*)&b[lane * 4];
    float4 o;
    o.x = fmaxf(di * acc.x + bb.x, 0.f);
    o.y = fmaxf(di * acc.y + bb.y, 0.f);
    o.z = fmaxf(di * acc.z + bb.z, 0.f);
    o.w = fmaxf(di * acc.w + bb.w, 0.f);
    *(float4*)&H[(size_t)g * 128 + lane * 4] = o;
}

// -------- layer-2 aggregation (bf16 G, 16 lanes/row, unroll 4) + mean-pool ----------

__global__ __launch_bounds__(256) void k_gather64_pool(const int* __restrict__ rowptr,
                                                       const int* __restrict__ rowend,
                                                       const int* __restrict__ csr,
                                                       const ushort_t* __restrict__ G,
                                                       const float* __restrict__ dinv,
                                                       const float* __restrict__ b,
                                                       const int* __restrict__ batch,
                                                       float* __restrict__ pool, int n) {
    __shared__ float po[16][68];
    __shared__ int pg[16];
    const int grp = threadIdx.x / 16;
    const int lane = threadIdx.x & 15;
    const int g = blockIdx.x * 16 + grp;

    float4 o = make_float4(0.f, 0.f, 0.f, 0.f);
    if (g < n) {
        const int beg = rowptr[g], end = rowend[g];
        float4 acc = bf4_to_f4(*(const uint2*)&G[(size_t)g * 64 + lane * 4]);
        int e = beg;
        for (; e + 3 < end; e += 4) {
            int s0 = csr[e], s1 = csr[e + 1], s2 = csr[e + 2], s3 = csr[e + 3];
            uint2 r0 = *(const uint2*)&G[(size_t)s0 * 64 + lane * 4];
            uint2 r1 = *(const uint2*)&G[(size_t)s1 * 64 + lane * 4];
            uint2 r2 = *(const uint2*)&G[(size_t)s2 * 64 + lane * 4];
            uint2 r3 = *(const uint2*)&G[(size_t)s3 * 64 + lane * 4];
            float4 a0 = bf4_to_f4(r0), a1 = bf4_to_f4(r1);
            float4 a2 = bf4_to_f4(r2), a3 = bf4_to_f4(r3);
            acc.x += (a0.x + a1.x) + (a2.x + a3.x);
            acc.y += (a0.y + a1.y) + (a2.y + a3.y);
            acc.z += (a0.z + a1.z) + (a2.z + a3.z);
            acc.w += (a0.w + a1.w) + (a2.w + a3.w);
        }
        for (; e < end; e++) {
            int s0 = csr[e];
            float4 a = bf4_to_f4(*(const uint2*)&G[(size_t)s0 * 64 + lane * 4]);
            acc.x += a.x; acc.y += a.y; acc.z += a.z; acc.w += a.w;
        }
        const float di = dinv[g];
        float4 bb = *(const float4*)&b[lane * 4];
        o.x = fmaxf(di * acc.x + bb.x, 0.f);
        o.y = fmaxf(di * acc.y + bb.y, 0.f);
        o.z = fmaxf(di * acc.z + bb.z, 0.f);
        o.w = fmaxf(di * acc.w + bb.w, 0.f);
    }
    if (lane == 0) pg[grp] = (g < n) ? batch[g] : -1;
    *(float4*)&po[grp][lane * 4] = o;
    __syncthreads();

    if (threadIdx.x < 64) {
        const int c = threadIdx.x;
        float run = 0.f;
        int cur = -1;
        for (int r = 0; r < 16; r++) {
            int gr = pg[r];
            if (gr < 0) continue;
            if (gr != cur) {
                if (cur >= 0) atomicAdd(&pool[cur * 64 + c], run);
                cur = gr;
                run = 0.f;
            }
            run += po[r][c];
        }
        if (cur >= 0) atomicAdd(&pool[cur * 64 + c], run);
    }
}

// -------------------- pooling tail --------------------

__global__ __launch_bounds__(64) void k_div_bs(const float* __restrict__ pool,
                                               const int* __restrict__ batch,
                                               float* __restrict__ out, int n) {
    int t = blockIdx.x * 64 + threadIdx.x;
    int g = t >> 6;
    int lo = 0, hi = n;
    while (lo < hi) { int m = (lo + hi) >> 1; if (batch[m] < g) lo = m + 1; else hi = m; }
    int lb = lo;
    lo = lb; hi = n;
    while (lo < hi) { int m = (lo + hi) >> 1; if (batch[m] <= g) lo = m + 1; else hi = m; }
    float c = (float)(lo - lb);
    c = c > 1.f ? c : 1.f;
    out[t] = pool[t] / c;
}

// -------------------- launch --------------------

extern "C" void kernel_launch(void* const* d_in, const int* in_sizes, int n_in,
                              void* d_out, int out_size, void* d_ws, size_t ws_size,
                              hipStream_t stream) {
    const float* x = (const float*)d_in[0];
    const int* edge = (const int*)d_in[1];
    const int* batch = (const int*)d_in[2];
    const float* W1 = (const float*)d_in[3];
    const float* b1 = (const float*)d_in[4];
    const float* W2 = (const float*)d_in[5];
    const float* b2 = (const float*)d_in[6];

    const int n = in_sizes[0] / 128;
    const int E = in_sizes[1] / 2;
    const int* src = edge;
    const int* dst = edge + E;
    const int nb = (n + 255) >> BSH;

    size_t nA = ((size_t)n + 255) & ~(size_t)255;
    float* dinv = (float*)d_ws;                 // nA
    int* rowptr = (int*)(dinv + nA);            // nA
    int* rowend = rowptr + nA;                  // nA
    int* bcnt = rowend + nA;                    // 512
    int* boff = bcnt + NBMAX;                   // 512
    int* bcur = boff + NBMAX;                   // 512
    float* pool = (float*)(bcur + NBMAX);       // 4096 (+256 pad)
    ushort_t* bufG = (ushort_t*)(pool + 4096 + 256);  // n*128 bf16 (25.6MB); pairs alias
    float* bufH = (float*)(bufG + (size_t)n * 128);   // n*128 f32
    int* csr = (int*)(bufH + (size_t)n * 128);        // E
    int2* pairs = (int2*)bufG;                        // E pairs (dead before gemm1)

    hipMemsetAsync(bcnt, 0, NBMAX * 4, stream);
    hipMemsetAsync(pool, 0, 4096 * 4, stream);

    // bucketed CSR build (+ dinv)
    int gE = (E + EPB - 1) / EPB;
    k_bhist<<<gE, 256, 0, stream>>>(dst, bcnt, E, nb);
    k_bscan<<<1, NBMAX, 0, stream>>>(bcnt, boff, bcur, nb);
    k_bscatter<<<gE, 256, 0, stream>>>(src, dst, bcur, pairs, E, nb);
    k_bcsr<<<nb, 256, 0, stream>>>(pairs, boff, bcur, rowptr, rowend, dinv, csr, n);

    // layer 1
    k_gemm_rb_bf<32, 128, 0><<<(n + 31) / 32, 256, 0, stream>>>(x, W1, dinv, bufG, n);
    k_gather128<<<(n + 7) / 8, 256, 0, stream>>>(rowptr, rowend, csr, bufG, dinv, b1,
                                                 bufH, n);

    // layer 2 (G2 overwrites G1 region, bf16 n*64)
    k_gemm_rb_bf<64, 64, 4><<<(n + 63) / 64, 256, 0, stream>>>(bufH, W2, dinv, bufG, n);
    k_gather64_pool<<<(n + 15) / 16, 256, 0, stream>>>(rowptr, rowend, csr, bufG, dinv,
                                                       b2, batch, pool, n);

    k_div_bs<<<64, 64, 0, stream>>>(pool, batch, (float*)d_out, n);
}

// Round 7
// 228.310 us; speedup vs baseline: 22.3567x; 1.2757x over previous
//
#include <hip/hip_runtime.h>

typedef unsigned short ushort_t;
typedef unsigned int uint_t;
typedef __attribute__((ext_vector_type(8))) short bf16x8;
typedef __attribute__((ext_vector_type(4))) float f32x4;

__device__ inline ushort_t bf16_rne(float f) {
    uint_t u = __float_as_uint(f);
    return (ushort_t)((u + 0x7FFFu + ((u >> 16) & 1u)) >> 16);
}

__device__ inline float4 bf4_to_f4(uint2 v) {
    float4 f;
    f.x = __uint_as_float(v.x << 16);
    f.y = __uint_as_float(v.x & 0xFFFF0000u);
    f.z = __uint_as_float(v.y << 16);
    f.w = __uint_as_float(v.y & 0xFFFF0000u);
    return f;
}

// ============ bucketed CSR build (bucket = dst >> 8, <=512 buckets) ============

#define BSH 8
#define NBMAX 512
#define EPB 4096

__global__ __launch_bounds__(256) void k_bhist(const int* __restrict__ dst,
                                               int* __restrict__ bcnt, int E, int nb) {
    __shared__ int h[NBMAX];
    const int tid = threadIdx.x;
    for (int i = tid; i < NBMAX; i += 256) h[i] = 0;
    __syncthreads();
    const int e0 = blockIdx.x * EPB;
    for (int i = tid; i < EPB; i += 256) {
        int e = e0 + i;
        if (e < E) atomicAdd(&h[dst[e] >> BSH], 1);
    }
    __syncthreads();
    for (int i = tid; i < nb; i += 256)
        if (h[i]) atomicAdd(&bcnt[i], h[i]);
}

__global__ __launch_bounds__(512) void k_bscan(const int* __restrict__ bcnt,
                                               int* __restrict__ boff,
                                               int* __restrict__ bcur, int nb) {
    __shared__ int a[NBMAX];
    const int t = threadIdx.x;
    int v = (t < nb) ? bcnt[t] : 0;
    a[t] = v;
    __syncthreads();
    for (int off = 1; off < NBMAX; off <<= 1) {
        int x = (t >= off) ? a[t - off] : 0;
        __syncthreads();
        a[t] += x;
        __syncthreads();
    }
    if (t < nb) {
        int excl = a[t] - v;
        boff[t] = excl;
        bcur[t] = excl;
    }
}

__global__ __launch_bounds__(256) void k_bscatter(const int* __restrict__ src,
                                                  const int* __restrict__ dst,
                                                  int* __restrict__ bcur,
                                                  int2* __restrict__ pairs, int E, int nb) {
    __shared__ int h[NBMAX];
    __shared__ int base[NBMAX];
    const int tid = threadIdx.x;
    for (int i = tid; i < NBMAX; i += 256) h[i] = 0;
    __syncthreads();
    const int e0 = blockIdx.x * EPB;
    for (int i = tid; i < EPB; i += 256) {
        int e = e0 + i;
        if (e < E) atomicAdd(&h[dst[e] >> BSH], 1);
    }
    __syncthreads();
    for (int b = tid; b < nb; b += 256) {
        int c = h[b];
        base[b] = c ? atomicAdd(&bcur[b], c) : 0;
        h[b] = 0;
    }
    __syncthreads();
    for (int i = tid; i < EPB; i += 256) {
        int e = e0 + i;
        if (e < E) {
            int s = src[e], d = dst[e];
            int bk = d >> BSH;
            int off = atomicAdd(&h[bk], 1);
            pairs[base[bk] + off] = make_int2(s, d);
        }
    }
}

__global__ __launch_bounds__(256) void k_bcsr(const int2* __restrict__ pairs,
                                              const int* __restrict__ boff,
                                              const int* __restrict__ bcurEnd,
                                              int* __restrict__ rowptr,
                                              int* __restrict__ rowend,
                                              float* __restrict__ dinv,
                                              int* __restrict__ csr, int n) {
    __shared__ int deg[256], sc[256], cur[256];
    const int t = threadIdx.x;
    const int b = blockIdx.x;
    const int beg = boff[b], end = bcurEnd[b];
    deg[t] = 0;
    __syncthreads();
    for (int i = beg + t; i < end; i += 256) {
        int2 p = pairs[i];
        atomicAdd(&deg[p.y & 255], 1);
    }
    __syncthreads();
    int dv = deg[t];
    sc[t] = dv;
    __syncthreads();
    for (int off = 1; off < 256; off <<= 1) {
        int x = (t >= off) ? sc[t - off] : 0;
        __syncthreads();
        sc[t] += x;
        __syncthreads();
    }
    int excl = sc[t] - dv;
    cur[t] = excl;
    int d = (b << BSH) + t;
    if (d < n) {
        int r = beg + excl;
        rowptr[d] = r;
        rowend[d] = r + dv;
        dinv[d] = rsqrtf((float)dv + 1.0f);
    }
    __syncthreads();
    for (int i = beg + t; i < end; i += 256) {
        int2 p = pairs[i];
        int off = atomicAdd(&cur[p.y & 255], 1);
        csr[beg + off] = p.x;
    }
}

// --------- weight prep: Wt[c][k] = bf16(W[k][c]) for both layers ---------

__global__ __launch_bounds__(256) void k_prep_w(const float* __restrict__ W1,
                                                const float* __restrict__ W2,
                                                ushort_t* __restrict__ Wt1,
                                                ushort_t* __restrict__ Wt2) {
    int idx = blockIdx.x * 256 + threadIdx.x;  // 96 blocks = 24576
    if (idx < 16384) {
        int k = idx >> 7, c = idx & 127;
        Wt1[c * 128 + k] = bf16_rne(W1[idx]);
    } else if (idx < 24576) {
        int j = idx - 16384;
        int k = j >> 6, c = j & 63;
        Wt2[c * 128 + k] = bf16_rne(W2[j]);
    }
}

// --------- MFMA GEMM: G[i][c] = bf16(dinv[i] * sum_k X[i][k]*W[k][c]) ---------
// Block: 128 rows x DOUT cols, 4 waves (2x2). Wave: 4 M-tiles x NT N-tiles of 16x16.
// mfma_f32_16x16x32_bf16: A row=lane&15, k=(lane>>4)*8+j (contig 8); B col=lane&15,
// same k; C/D col=lane&15, row=(lane>>4)*4+reg  [m89-verified layout].

template <int DOUT, bool IN_BF16>
__global__ __launch_bounds__(256) void k_gemm_mfma(const void* __restrict__ Xv,
                                                   const ushort_t* __restrict__ Wt,
                                                   const float* __restrict__ dinv,
                                                   ushort_t* __restrict__ G, int n) {
    constexpr int KP = 136;      // padded row stride (bf16): 272B -> bank-shift 4/row
    constexpr int NW = DOUT / 2; // cols per wave
    constexpr int NT = NW / 16;  // n-tiles per wave
    __shared__ ushort_t Xs[128 * KP];
    __shared__ ushort_t Ws[DOUT * KP];

    const int tid = threadIdx.x;
    const int row0 = blockIdx.x * 128;

    // stage X tile (convert f32->bf16 if needed)
    if (!IN_BF16) {
        const float* X = (const float*)Xv;
#pragma unroll
        for (int i = 0; i < 16; i++) {
            int idx = tid * 4 + i * 1024;
            int r = idx >> 7, k = idx & 127;
            int gr = row0 + r;
            float4 v = make_float4(0.f, 0.f, 0.f, 0.f);
            if (gr < n) v = *(const float4*)&X[(size_t)gr * 128 + k];
            ushort4 o;
            o.x = bf16_rne(v.x); o.y = bf16_rne(v.y);
            o.z = bf16_rne(v.z); o.w = bf16_rne(v.w);
            *(ushort4*)&Xs[r * KP + k] = o;
        }
    } else {
        const ushort_t* X = (const ushort_t*)Xv;
#pragma unroll
        for (int i = 0; i < 8; i++) {
            int idx = tid * 8 + i * 2048;
            int r = idx >> 7, k = idx & 127;
            int gr = row0 + r;
            uint4 v = make_uint4(0u, 0u, 0u, 0u);
            if (gr < n) v = *(const uint4*)&X[(size_t)gr * 128 + k];
            *(uint4*)&Xs[r * KP + k] = v;
        }
    }
    // stage Wt (already bf16, [DOUT][128] linear)
    constexpr int WI = (DOUT * 128) / 2048;
#pragma unroll
    for (int i = 0; i < WI; i++) {
        int idx = tid * 8 + i * 2048;
        int r = idx >> 7, k = idx & 127;
        *(uint4*)&Ws[r * KP + k] = *(const uint4*)&Wt[idx];
    }
    __syncthreads();

    const int lane = tid & 63;
    const int wid = tid >> 6;
    const int wm = wid & 1, wn = wid >> 1;  // 2x2 wave grid
    const int lr = lane & 15;               // A-row / B-col / D-col
    const int kg = lane >> 4;               // k-group

    f32x4 acc[4][NT];
#pragma unroll
    for (int mi = 0; mi < 4; mi++)
#pragma unroll
        for (int ni = 0; ni < NT; ni++)
#pragma unroll
            for (int q = 0; q < 4; q++) acc[mi][ni][q] = 0.f;

    const ushort_t* xb = &Xs[(wm * 64 + lr) * KP + kg * 8];
    const ushort_t* wb = &Ws[(wn * NW + lr) * KP + kg * 8];

#pragma unroll
    for (int ks = 0; ks < 4; ks++) {
        bf16x8 a[4], b[NT];
#pragma unroll
        for (int mi = 0; mi < 4; mi++)
            a[mi] = *(const bf16x8*)&xb[mi * 16 * KP + ks * 32];
#pragma unroll
        for (int ni = 0; ni < NT; ni++)
            b[ni] = *(const bf16x8*)&wb[ni * 16 * KP + ks * 32];
#pragma unroll
        for (int mi = 0; mi < 4; mi++)
#pragma unroll
            for (int ni = 0; ni < NT; ni++)
                acc[mi][ni] = __builtin_amdgcn_mfma_f32_16x16x32_bf16(
                    a[mi], b[ni], acc[mi][ni], 0, 0, 0);
    }

#pragma unroll
    for (int mi = 0; mi < 4; mi++) {
        int r0 = row0 + wm * 64 + mi * 16 + kg * 4;
#pragma unroll
        for (int r = 0; r < 4; r++) {
            int gr = r0 + r;
            if (gr < n) {
                float s = dinv[gr];
#pragma unroll
                for (int ni = 0; ni < NT; ni++) {
                    int c = wn * NW + ni * 16 + lr;
                    G[(size_t)gr * DOUT + c] = bf16_rne(s * acc[mi][ni][r]);
                }
            }
        }
    }
}

// ------------- layer-1 aggregation: 32 lanes/row, bf16 G, bf16 H out -------------

__global__ __launch_bounds__(256) void k_gather128(const int* __restrict__ rowptr,
                                                   const int* __restrict__ rowend,
                                                   const int* __restrict__ csr,
                                                   const ushort_t* __restrict__ G,
                                                   const float* __restrict__ dinv,
                                                   const float* __restrict__ b,
                                                   ushort_t* __restrict__ H, int n) {
    const int g = blockIdx.x * 8 + threadIdx.x / 32;
    const int lane = threadIdx.x & 31;
    if (g >= n) return;
    const int beg = rowptr[g], end = rowend[g];

    float4 acc = bf4_to_f4(*(const uint2*)&G[(size_t)g * 128 + lane * 4]);  // self
    int e = beg;
    for (; e + 3 < end; e += 4) {
        int s0 = csr[e], s1 = csr[e + 1], s2 = csr[e + 2], s3 = csr[e + 3];
        uint2 r0 = *(const uint2*)&G[(size_t)s0 * 128 + lane * 4];
        uint2 r1 = *(const uint2*)&G[(size_t)s1 * 128 + lane * 4];
        uint2 r2 = *(const uint2*)&G[(size_t)s2 * 128 + lane * 4];
        uint2 r3 = *(const uint2*)&G[(size_t)s3 * 128 + lane * 4];
        float4 a0 = bf4_to_f4(r0), a1 = bf4_to_f4(r1);
        float4 a2 = bf4_to_f4(r2), a3 = bf4_to_f4(r3);
        acc.x += (a0.x + a1.x) + (a2.x + a3.x);
        acc.y += (a0.y + a1.y) + (a2.y + a3.y);
        acc.z += (a0.z + a1.z) + (a2.z + a3.z);
        acc.w += (a0.w + a1.w) + (a2.w + a3.w);
    }
    for (; e < end; e++) {
        int s0 = csr[e];
        float4 a = bf4_to_f4(*(const uint2*)&G[(size_t)s0 * 128 + lane * 4]);
        acc.x += a.x; acc.y += a.y; acc.z += a.z; acc.w += a.w;
    }
    const float di = dinv[g];
    float4 bb = *(const float4*)&b[lane * 4];
    ushort4 o;
    o.x = bf16_rne(fmaxf(di * acc.x + bb.x, 0.f));
    o.y = bf16_rne(fmaxf(di * acc.y + bb.y, 0.f));
    o.z = bf16_rne(fmaxf(di * acc.z + bb.z, 0.f));
    o.w = bf16_rne(fmaxf(di * acc.w + bb.w, 0.f));
    *(ushort4*)&H[(size_t)g * 128 + lane * 4] = o;
}

// -------- layer-2 aggregation (bf16 G, 16 lanes/row, unroll 4) + mean-pool ----------

__global__ __launch_bounds__(256) void k_gather64_pool(const int* __restrict__ rowptr,
                                                       const int* __restrict__ rowend,
                                                       const int* __restrict__ csr,
                                                       const ushort_t* __restrict__ G,
                                                       const float* __restrict__ dinv,
                                                       const float* __restrict__ b,
                                                       const int* __restrict__ batch,
                                                       float* __restrict__ pool, int n) {
    __shared__ float po[16][68];
    __shared__ int pg[16];
    const int grp = threadIdx.x / 16;
    const int lane = threadIdx.x & 15;
    const int g = blockIdx.x * 16 + grp;

    float4 o = make_float4(0.f, 0.f, 0.f, 0.f);
    if (g < n) {
        const int beg = rowptr[g], end = rowend[g];
        float4 acc = bf4_to_f4(*(const uint2*)&G[(size_t)g * 64 + lane * 4]);
        int e = beg;
        for (; e + 3 < end; e += 4) {
            int s0 = csr[e], s1 = csr[e + 1], s2 = csr[e + 2], s3 = csr[e + 3];
            uint2 r0 = *(const uint2*)&G[(size_t)s0 * 64 + lane * 4];
            uint2 r1 = *(const uint2*)&G[(size_t)s1 * 64 + lane * 4];
            uint2 r2 = *(const uint2*)&G[(size_t)s2 * 64 + lane * 4];
            uint2 r3 = *(const uint2*)&G[(size_t)s3 * 64 + lane * 4];
            float4 a0 = bf4_to_f4(r0), a1 = bf4_to_f4(r1);
            float4 a2 = bf4_to_f4(r2), a3 = bf4_to_f4(r3);
            acc.x += (a0.x + a1.x) + (a2.x + a3.x);
            acc.y += (a0.y + a1.y) + (a2.y + a3.y);
            acc.z += (a0.z + a1.z) + (a2.z + a3.z);
            acc.w += (a0.w + a1.w) + (a2.w + a3.w);
        }
        for (; e < end; e++) {
            int s0 = csr[e];
            float4 a = bf4_to_f4(*(const uint2*)&G[(size_t)s0 * 64 + lane * 4]);
            acc.x += a.x; acc.y += a.y; acc.z += a.z; acc.w += a.w;
        }
        const float di = dinv[g];
        float4 bb = *(const float4*)&b[lane * 4];
        o.x = fmaxf(di * acc.x + bb.x, 0.f);
        o.y = fmaxf(di * acc.y + bb.y, 0.f);
        o.z = fmaxf(di * acc.z + bb.z, 0.f);
        o.w = fmaxf(di * acc.w + bb.w, 0.f);
    }
    if (lane == 0) pg[grp] = (g < n) ? batch[g] : -1;
    *(float4*)&po[grp][lane * 4] = o;
    __syncthreads();

    if (threadIdx.x < 64) {
        const int c = threadIdx.x;
        float run = 0.f;
        int cur = -1;
        for (int r = 0; r < 16; r++) {
            int gr = pg[r];
            if (gr < 0) continue;
            if (gr != cur) {
                if (cur >= 0) atomicAdd(&pool[cur * 64 + c], run);
                cur = gr;
                run = 0.f;
            }
            run += po[r][c];
        }
        if (cur >= 0) atomicAdd(&pool[cur * 64 + c], run);
    }
}

// -------------------- pooling tail --------------------

__global__ __launch_bounds__(64) void k_div_bs(const float* __restrict__ pool,
                                               const int* __restrict__ batch,
                                               float* __restrict__ out, int n) {
    int t = blockIdx.x * 64 + threadIdx.x;
    int g = t >> 6;
    int lo = 0, hi = n;
    while (lo < hi) { int m = (lo + hi) >> 1; if (batch[m] < g) lo = m + 1; else hi = m; }
    int lb = lo;
    lo = lb; hi = n;
    while (lo < hi) { int m = (lo + hi) >> 1; if (batch[m] <= g) lo = m + 1; else hi = m; }
    float c = (float)(lo - lb);
    c = c > 1.f ? c : 1.f;
    out[t] = pool[t] / c;
}

// -------------------- launch --------------------

extern "C" void kernel_launch(void* const* d_in, const int* in_sizes, int n_in,
                              void* d_out, int out_size, void* d_ws, size_t ws_size,
                              hipStream_t stream) {
    const float* x = (const float*)d_in[0];
    const int* edge = (const int*)d_in[1];
    const int* batch = (const int*)d_in[2];
    const float* W1 = (const float*)d_in[3];
    const float* b1 = (const float*)d_in[4];
    const float* W2 = (const float*)d_in[5];
    const float* b2 = (const float*)d_in[6];

    const int n = in_sizes[0] / 128;
    const int E = in_sizes[1] / 2;
    const int* src = edge;
    const int* dst = edge + E;
    const int nb = (n + 255) >> BSH;

    size_t nA = ((size_t)n + 255) & ~(size_t)255;
    float* dinv = (float*)d_ws;                      // nA
    int* rowptr = (int*)(dinv + nA);                 // nA
    int* rowend = rowptr + nA;                       // nA
    int* bcnt = rowend + nA;                         // 512
    int* boff = bcnt + NBMAX;                        // 512
    int* bcur = boff + NBMAX;                        // 512
    float* pool = (float*)(bcur + NBMAX);            // 4096 + 256 pad
    ushort_t* Wt1 = (ushort_t*)(pool + 4096 + 256);  // 16384 bf16
    ushort_t* Wt2 = Wt1 + 16384;                     // 8192 bf16
    ushort_t* bufG = Wt2 + 8192;                     // n*128 bf16 (pairs alias)
    ushort_t* bufH = bufG + (size_t)n * 128;         // n*128 bf16
    int* csr = (int*)(bufH + (size_t)n * 128);       // E
    int2* pairs = (int2*)bufG;                       // E*8B <= n*256B, dead pre-gemm1

    hipMemsetAsync(bcnt, 0, NBMAX * 4, stream);
    hipMemsetAsync(pool, 0, 4096 * 4, stream);

    k_prep_w<<<96, 256, 0, stream>>>(W1, W2, Wt1, Wt2);

    // bucketed CSR build (+ dinv)
    int gE = (E + EPB - 1) / EPB;
    k_bhist<<<gE, 256, 0, stream>>>(dst, bcnt, E, nb);
    k_bscan<<<1, NBMAX, 0, stream>>>(bcnt, boff, bcur, nb);
    k_bscatter<<<gE, 256, 0, stream>>>(src, dst, bcur, pairs, E, nb);
    k_bcsr<<<nb, 256, 0, stream>>>(pairs, boff, bcur, rowptr, rowend, dinv, csr, n);

    // layer 1: MFMA GEMM (f32 in, bf16 out) -> gather (bf16 H out)
    k_gemm_mfma<128, false><<<(n + 127) / 128, 256, 0, stream>>>(x, Wt1, dinv, bufG, n);
    k_gather128<<<(n + 7) / 8, 256, 0, stream>>>(rowptr, rowend, csr, bufG, dinv, b1,
                                                 bufH, n);

    // layer 2: MFMA GEMM (bf16 in, bf16 out) -> gather + pool
    k_gemm_mfma<64, true><<<(n + 127) / 128, 256, 0, stream>>>(bufH, Wt2, dinv, bufG, n);
    k_gather64_pool<<<(n + 15) / 16, 256, 0, stream>>>(rowptr, rowend, csr, bufG, dinv,
                                                       b2, batch, pool, n);

    k_div_bs<<<64, 64, 0, stream>>>(pool, batch, (float*)d_out, n);
}